// Round 2
// baseline (537.473 us; speedup 1.0000x reference)
//
#include <hip/hip_runtime.h>
#include <math.h>

// MambaBlock: 4-direction 2D selective scan + fuse + LN + SiLU
// B=2, H=W=128, D_MODEL=64, D_INNER=128, D_STATE=16, DT_RANK=4, D_CONV=4
//
// R2: fused front kernel (in-proj + conv + xp-proj + SCAN all in one block's LDS).
// R1 bug: ws offsets computed in elements vs bytes -> UC/Zs/DBL/YF overlapped ->
// bf16 writes misread as fp32 -> NaN. Fused design needs only YF(33.5MB)+M in ws.
// Learned: >64KB static LDS launches fine on gfx950 (K3 @136KB executed).
//
//  K0: M[dir][d][o] = sum_j out_w[dir][j][d]*fuse_w[o][dir*64+j]  (fold out-proj+fuse)
//  K1: per (dir,seq) block: gather -> in-proj (u,z) -> conv4+silu -> xp-proj -> scan
//      writes yf = (y + uc*Dp)*silu(z) as bf16 to YF
//  K3: per 64-token tile: gather 4-dir yf, GEMM vs M (512->64), +bias, LN, SiLU, store

__device__ __forceinline__ unsigned short f2bf(float f) {
  unsigned int u = __float_as_uint(f);
  u += 0x7fffu + ((u >> 16) & 1u);
  return (unsigned short)(u >> 16);
}
__device__ __forceinline__ float bf2f(unsigned short h) {
  return __uint_as_float(((unsigned int)h) << 16);
}
__device__ __forceinline__ float siluf(float x) { return x / (1.f + __expf(-x)); }

// ---------------------------------------------------------------- K0
__global__ void k0_prepM(const float* __restrict__ out_w, const float* __restrict__ fuse_w,
                         float* __restrict__ M) {
  int idx = blockIdx.x * 256 + threadIdx.x;   // 4*128*64 = 32768
  int o = idx & 63;
  int d = (idx >> 6) & 127;
  int dir = idx >> 13;
  float acc = 0.f;
  #pragma unroll 8
  for (int j = 0; j < 64; ++j)
    acc += out_w[(dir*64 + j)*128 + d] * fuse_w[o*256 + dir*64 + j];
  M[idx] = acc;   // layout [dir][d][o]
}

// ---------------------------------------------------------------- K1 (fused)
// LDS: sx   fp32 [64][128]   @0       32768B  (x tile; reused for xp_w [36][132])
//      sUC  fp32 [128][132]  @32768   67584B  (u_pre -> uc)
//      sZ   u16  [128][136]  @100352  34816B  (silu(z) bf16 -> later yf bf16)
//      sDBL fp32 [128][40]   @135168  20480B  (dbl; first 4KB doubles as sW stage)
// total 155648 <= 163840
__global__ __launch_bounds__(256, 1) void k1_front(
    const float* __restrict__ x, const float* __restrict__ in_w,
    const float* __restrict__ conv_w, const float* __restrict__ conv_b,
    const float* __restrict__ xp_w,
    const float* __restrict__ dtp_w, const float* __restrict__ dtp_b,
    const float* __restrict__ A_log, const float* __restrict__ Dp,
    unsigned short* __restrict__ YF)
{
  __shared__ __align__(16) char smem[155648];
  float* sx            = (float*)smem;                     // 8192 floats
  float* sUC           = (float*)(smem + 32768);           // [128][132]
  unsigned short* sZ   = (unsigned short*)(smem + 100352); // [128][136]
  float* sDBL          = (float*)(smem + 135168);          // [128][40]
  float* sW            = (float*)(smem + 135168);          // 1024 floats (phase-2 stage)

  const int tid = threadIdx.x;
  const int dir = blockIdx.x >> 8;
  const int n   = blockIdx.x & 255;
  const int b   = n >> 7;
  const int r   = n & 127;
  const float* xb = x + (size_t)b * (64*128*128);

  // ---- phase 1: gather tokens into sx[c][l] ----
  if (dir == 0) {
    for (int f = tid*4; f < 8192; f += 1024) {
      int c = f >> 7, l = f & 127;
      float4 v = *(const float4*)(xb + ((size_t)c*128 + r)*128 + l);
      *(float4*)(sx + c*128 + l) = v;
    }
  } else if (dir == 1) {
    for (int f = tid*4; f < 8192; f += 1024) {
      int c = f >> 7, w = f & 127;
      float4 v = *(const float4*)(xb + ((size_t)c*128 + r)*128 + w);
      float* row = sx + c*128;
      row[127-w] = v.x; row[126-w] = v.y; row[125-w] = v.z; row[124-w] = v.w;
    }
  } else if (dir == 2) {
    for (int f = tid; f < 8192; f += 256) {
      int c = f >> 7, l = f & 127;
      sx[c*128 + l] = xb[((size_t)c*128 + l)*128 + r];
    }
  } else {
    for (int f = tid; f < 8192; f += 256) {
      int c = f >> 7, l = f & 127;
      sx[c*128 + l] = xb[((size_t)c*128 + (127-l))*128 + r];
    }
  }
  __syncthreads();

  // ---- phase 2: in-projection, 256 rows (u: 0..127 -> sUC, z: 128..255 -> sZ) ----
  const float* w_in = in_w + (size_t)dir * (256*64);
  const int dgrp = tid >> 3;     // 0..31 -> d0 = dgrp*8
  const int lgrp = tid & 7;      // l = lgrp*4 + ii*32 + q
  const int d0 = dgrp * 8;

  float acc[16][8];
  #pragma unroll
  for (int i = 0; i < 16; ++i)
    #pragma unroll
    for (int jj = 0; jj < 8; ++jj) acc[i][jj] = 0.f;

  for (int c0 = 0; c0 < 64; c0 += 4) {
    __syncthreads();
    {
      float4 wv = *(const float4*)(w_in + tid*64 + c0);
      sW[tid] = wv.x; sW[256+tid] = wv.y; sW[512+tid] = wv.z; sW[768+tid] = wv.w;
    }
    __syncthreads();
    #pragma unroll
    for (int j = 0; j < 4; ++j) {
      float wreg[8];
      #pragma unroll
      for (int dd = 0; dd < 8; ++dd) wreg[dd] = sW[j*256 + d0 + dd];
      #pragma unroll
      for (int ii = 0; ii < 4; ++ii) {
        float4 av = *(const float4*)(sx + (c0+j)*128 + lgrp*4 + ii*32);
        #pragma unroll
        for (int dd = 0; dd < 8; ++dd) {
          acc[ii*4+0][dd] += av.x * wreg[dd];
          acc[ii*4+1][dd] += av.y * wreg[dd];
          acc[ii*4+2][dd] += av.z * wreg[dd];
          acc[ii*4+3][dd] += av.w * wreg[dd];
        }
      }
    }
  }
  // writeout: sUC (u rows) / sZ (silu(z) rows). sUC/sZ disjoint from sW/sx -> no
  // extra barrier needed before laggards finish reading sW.
  if (d0 < 128) {
    #pragma unroll
    for (int ii = 0; ii < 4; ++ii)
      #pragma unroll
      for (int q = 0; q < 4; ++q) {
        int l = lgrp*4 + ii*32 + q;
        float4 v0, v1;
        v0.x = acc[ii*4+q][0]; v0.y = acc[ii*4+q][1]; v0.z = acc[ii*4+q][2]; v0.w = acc[ii*4+q][3];
        v1.x = acc[ii*4+q][4]; v1.y = acc[ii*4+q][5]; v1.z = acc[ii*4+q][6]; v1.w = acc[ii*4+q][7];
        *(float4*)(sUC + l*132 + d0) = v0;
        *(float4*)(sUC + l*132 + d0 + 4) = v1;
      }
  } else {
    const int dz = d0 - 128;
    #pragma unroll
    for (int ii = 0; ii < 4; ++ii)
      #pragma unroll
      for (int q = 0; q < 4; ++q) {
        int l = lgrp*4 + ii*32 + q;
        unsigned int pk[4];
        #pragma unroll
        for (int p = 0; p < 4; ++p) {
          unsigned short lo = f2bf(siluf(acc[ii*4+q][p*2+0]));
          unsigned short hi = f2bf(siluf(acc[ii*4+q][p*2+1]));
          pk[p] = (unsigned int)lo | ((unsigned int)hi << 16);
        }
        uint4 u4; u4.x = pk[0]; u4.y = pk[1]; u4.z = pk[2]; u4.w = pk[3];
        *(uint4*)(sZ + (size_t)l*136 + dz) = u4;
      }
  }
  __syncthreads();

  // ---- phase 3: causal conv-4 + silu, in place in sUC ----
  {
    const int d = tid & 127;
    const int half = tid >> 7;
    const int lc0 = half * 64;
    const float* cw = conv_w + (size_t)(dir*128 + d)*4;
    const float c0w = cw[0], c1w = cw[1], c2w = cw[2], c3w = cw[3];
    const float cb = conv_b[dir*128 + d];
    float p0 = half ? sUC[(lc0-3)*132 + d] : 0.f;
    float p1 = half ? sUC[(lc0-2)*132 + d] : 0.f;
    float p2 = half ? sUC[(lc0-1)*132 + d] : 0.f;
    __syncthreads();
    for (int l = lc0; l < lc0 + 64; ++l) {
      float cur = sUC[l*132 + d];
      float v = cb + c0w*p0 + c1w*p1 + c2w*p2 + c3w*cur;
      sUC[l*132 + d] = siluf(v);
      p0 = p1; p1 = p2; p2 = cur;
    }
  }
  __syncthreads();

  // ---- phase 4: xp projection -> sDBL[l][0..35] (stride 40) ----
  {
    const float* wxp = xp_w + (size_t)dir * (36*128);
    float* sXW = sx;  // reuse token region (x no longer needed)
    for (int f = tid; f < 36*128; f += 256) {
      int rr = f >> 7, dc = f & 127;
      sXW[rr*132 + dc] = wxp[f];
    }
    __syncthreads();
    const int rgrp = tid & 3;
    const int lg = tid >> 2;          // rows lg and lg+64
    const int r0 = rgrp * 9;
    float xa0[9], xa1[9];
    #pragma unroll
    for (int rr = 0; rr < 9; ++rr) { xa0[rr] = 0.f; xa1[rr] = 0.f; }
    for (int dq = 0; dq < 128; dq += 4) {
      float4 a0 = *(const float4*)(sUC + lg*132 + dq);
      float4 a1 = *(const float4*)(sUC + (lg+64)*132 + dq);
      #pragma unroll
      for (int rr = 0; rr < 9; ++rr) {
        float4 wv = *(const float4*)(sXW + (r0+rr)*132 + dq);
        xa0[rr] += a0.x*wv.x + a0.y*wv.y + a0.z*wv.z + a0.w*wv.w;
        xa1[rr] += a1.x*wv.x + a1.y*wv.y + a1.z*wv.z + a1.w*wv.w;
      }
    }
    #pragma unroll
    for (int rr = 0; rr < 9; ++rr) {
      sDBL[lg*40 + r0 + rr]      = xa0[rr];
      sDBL[(lg+64)*40 + r0 + rr] = xa1[rr];
    }
  }
  __syncthreads();

  // ---- phase 5: selective scan. 2 threads per channel, 8 states each ----
  {
    const int d = tid >> 1;
    const int p = tid & 1;
    const float* dw = dtp_w + (size_t)(dir*128 + d) * 4;
    const float w0 = dw[0], w1 = dw[1], w2 = dw[2], w3 = dw[3];
    const float db = dtp_b[dir*128 + d];
    const float dpv = Dp[dir*128 + d];

    float Av[8];
    bool fast = true;
    #pragma unroll
    for (int j = 0; j < 8; ++j) {
      float a = -__expf(A_log[((size_t)(dir*128 + d))*16 + p*8 + j]);
      Av[j] = a;
      if (fabsf((-a) - (float)(p*8 + j + 1)) > 1e-3f) fast = false;
    }

    float h[8];
    #pragma unroll
    for (int j = 0; j < 8; ++j) h[j] = 0.f;

    if (fast) {
      // A[s] == -(s+1): decay = E^(s+1), E = exp(-dt); p=1 half seeds at E^8
      for (int l = 0; l < 128; ++l) {
        const float4* q = (const float4*)(sDBL + l*40);
        float4 q0 = q[0];
        float4 tb0 = q[1 + 2*p], tb1 = q[2 + 2*p];
        float4 tc0 = q[5 + 2*p], tc1 = q[6 + 2*p];
        float Bv[8] = {tb0.x,tb0.y,tb0.z,tb0.w, tb1.x,tb1.y,tb1.z,tb1.w};
        float Cv[8] = {tc0.x,tc0.y,tc0.z,tc0.w, tc1.x,tc1.y,tc1.z,tc1.w};
        float dr = q0.x*w0 + q0.y*w1 + q0.z*w2 + q0.w*w3 + db;
        float dt = (dr > 20.f) ? dr : log1pf(__expf(dr));
        float u = sUC[l*132 + d];
        float dtu = dt * u;
        float E = __expf(-dt);
        float E2 = E*E, E4 = E2*E2, E8 = E4*E4;
        float e = p ? E8 : 1.f;
        float yp = 0.f;
        #pragma unroll
        for (int j = 0; j < 8; ++j) {
          e *= E;
          h[j] = h[j]*e + dtu*Bv[j];
          yp += h[j]*Cv[j];
        }
        float ysum = yp + __shfl_xor(yp, 1, 64);
        if (p == 0) {
          float z = bf2f(sZ[l*136 + d]);
          sZ[l*136 + d] = f2bf((ysum + u*dpv) * z);
        }
      }
    } else {
      for (int l = 0; l < 128; ++l) {
        const float4* q = (const float4*)(sDBL + l*40);
        float4 q0 = q[0];
        float4 tb0 = q[1 + 2*p], tb1 = q[2 + 2*p];
        float4 tc0 = q[5 + 2*p], tc1 = q[6 + 2*p];
        float Bv[8] = {tb0.x,tb0.y,tb0.z,tb0.w, tb1.x,tb1.y,tb1.z,tb1.w};
        float Cv[8] = {tc0.x,tc0.y,tc0.z,tc0.w, tc1.x,tc1.y,tc1.z,tc1.w};
        float dr = q0.x*w0 + q0.y*w1 + q0.z*w2 + q0.w*w3 + db;
        float dt = (dr > 20.f) ? dr : log1pf(__expf(dr));
        float u = sUC[l*132 + d];
        float dtu = dt * u;
        float yp = 0.f;
        #pragma unroll
        for (int j = 0; j < 8; ++j) {
          float ej = __expf(dt*Av[j]);
          h[j] = h[j]*ej + dtu*Bv[j];
          yp += h[j]*Cv[j];
        }
        float ysum = yp + __shfl_xor(yp, 1, 64);
        if (p == 0) {
          float z = bf2f(sZ[l*136 + d]);
          sZ[l*136 + d] = f2bf((ysum + u*dpv) * z);
        }
      }
    }
  }
  __syncthreads();

  // ---- phase 6: vectorized YF writeout from sZ ----
  {
    unsigned short* YFn = YF + (size_t)(dir*256 + n) * (128*128);
    for (int f = tid*8; f < 16384; f += 2048) {
      int l = f >> 7, dz = f & 127;
      uint4 v = *(const uint4*)(sZ + l*136 + dz);
      *(uint4*)(YFn + f) = v;
    }
  }
}

// ---------------------------------------------------------------- K3
__global__ __launch_bounds__(256, 1) void k3_fuse(
    const unsigned short* __restrict__ YF, const float* __restrict__ M,
    const float* __restrict__ fuse_b, const float* __restrict__ ln_g,
    const float* __restrict__ ln_b, float* __restrict__ out)
{
  __shared__ __align__(16) char smem[136192];
  float* scy = (float*)smem;              // [64][260]
  float* sMT = (float*)(smem + 66560);    // [256][68]

  const int tid = threadIdx.x;
  const int blk = blockIdx.x;             // 512
  const int b = blk >> 8;
  const int rr2 = blk & 255;
  const int h = rr2 >> 1;
  const int w0 = (rr2 & 1) * 64;

  const int tokgrp = tid >> 3;            // 0..31 (toks tokgrp and tokgrp+32)
  const int ogrp = tid & 7;
  const int o0 = ogrp * 8;

  float acc[2][8];
  #pragma unroll
  for (int i = 0; i < 8; ++i) { acc[0][i] = 0.f; acc[1][i] = 0.f; }

  for (int pass = 0; pass < 2; ++pass) {
    __syncthreads();
    for (int f = tid; f < 16384; f += 256) {
      int j = f >> 6, o = f & 63;
      int dirl = j >> 7, dd = j & 127;
      sMT[j*68 + o] = M[(size_t)((pass*2 + dirl)*128 + dd)*64 + o];
    }
    for (int f = tid*8; f < 64*256; f += 2048) {
      int tok = f >> 8;
      int j = f & 255;
      int dirl = j >> 7, dd = j & 127;
      int dirg = pass*2 + dirl;
      size_t base;
      if      (dirg == 0) base = ((size_t)(0*256 + b*128 + h)*128 + (w0 + tok)) * 128;
      else if (dirg == 1) base = ((size_t)(1*256 + b*128 + h)*128 + (127 - w0 - tok)) * 128;
      else if (dirg == 2) base = ((size_t)(2*256 + b*128 + w0 + tok)*128 + h) * 128;
      else                base = ((size_t)(3*256 + b*128 + w0 + tok)*128 + (127 - h)) * 128;
      uint4 raw = *(const uint4*)(YF + base + dd);
      float* dst = scy + tok*260 + j;
      dst[0] = __uint_as_float(raw.x << 16);
      dst[1] = __uint_as_float(raw.x & 0xffff0000u);
      dst[2] = __uint_as_float(raw.y << 16);
      dst[3] = __uint_as_float(raw.y & 0xffff0000u);
      dst[4] = __uint_as_float(raw.z << 16);
      dst[5] = __uint_as_float(raw.z & 0xffff0000u);
      dst[6] = __uint_as_float(raw.w << 16);
      dst[7] = __uint_as_float(raw.w & 0xffff0000u);
    }
    __syncthreads();
    const float* arow0 = scy + tokgrp*260;
    const float* arow1 = scy + (tokgrp+32)*260;
    for (int j0 = 0; j0 < 256; j0 += 4) {
      float4 a0 = *(const float4*)(arow0 + j0);
      float4 a1 = *(const float4*)(arow1 + j0);
      float aa0[4] = {a0.x, a0.y, a0.z, a0.w};
      float aa1[4] = {a1.x, a1.y, a1.z, a1.w};
      #pragma unroll
      for (int jj = 0; jj < 4; ++jj) {
        const float* wr = sMT + (j0+jj)*68 + o0;
        float4 wv0 = *(const float4*)(wr);
        float4 wv1 = *(const float4*)(wr + 4);
        float av0 = aa0[jj], av1 = aa1[jj];
        acc[0][0]+=av0*wv0.x; acc[0][1]+=av0*wv0.y; acc[0][2]+=av0*wv0.z; acc[0][3]+=av0*wv0.w;
        acc[0][4]+=av0*wv1.x; acc[0][5]+=av0*wv1.y; acc[0][6]+=av0*wv1.z; acc[0][7]+=av0*wv1.w;
        acc[1][0]+=av1*wv0.x; acc[1][1]+=av1*wv0.y; acc[1][2]+=av1*wv0.z; acc[1][3]+=av1*wv0.w;
        acc[1][4]+=av1*wv1.x; acc[1][5]+=av1*wv1.y; acc[1][6]+=av1*wv1.z; acc[1][7]+=av1*wv1.w;
      }
    }
  }

  float fb[8], g8[8], bb[8];
  #pragma unroll
  for (int i = 0; i < 8; ++i) { fb[i]=fuse_b[o0+i]; g8[i]=ln_g[o0+i]; bb[i]=ln_b[o0+i]; }
  #pragma unroll
  for (int tt = 0; tt < 2; ++tt) {
    float fv[8]; float s1 = 0.f, s2 = 0.f;
    #pragma unroll
    for (int i = 0; i < 8; ++i) { float v = acc[tt][i] + fb[i]; fv[i] = v; s1 += v; s2 += v*v; }
    #pragma unroll
    for (int m = 1; m < 8; m <<= 1) { s1 += __shfl_xor(s1, m, 64); s2 += __shfl_xor(s2, m, 64); }
    float mu = s1 * (1.f/64.f);
    float var = s2 * (1.f/64.f) - mu*mu;
    float rs = rsqrtf(var + 1e-5f);
    int w = w0 + tokgrp + tt*32;
    #pragma unroll
    for (int i = 0; i < 8; ++i) {
      float v = (fv[i] - mu) * rs * g8[i] + bb[i];
      v = siluf(v);
      out[((size_t)(b*64 + o0 + i)*128 + h)*128 + w] = v;
    }
  }
}

// ---------------------------------------------------------------- host
extern "C" void kernel_launch(void* const* d_in, const int* in_sizes, int n_in,
                              void* d_out, int out_size, void* d_ws, size_t ws_size,
                              hipStream_t stream) {
  const float* x      = (const float*)d_in[0];
  const float* in_w   = (const float*)d_in[1];
  const float* conv_w = (const float*)d_in[2];
  const float* conv_b = (const float*)d_in[3];
  const float* xp_w   = (const float*)d_in[4];
  const float* dtp_w  = (const float*)d_in[5];
  const float* dtp_b  = (const float*)d_in[6];
  const float* A_log  = (const float*)d_in[7];
  const float* Dp     = (const float*)d_in[8];
  const float* out_w  = (const float*)d_in[9];
  const float* fuse_w = (const float*)d_in[10];
  const float* fuse_b = (const float*)d_in[11];
  const float* ln_g   = (const float*)d_in[12];
  const float* ln_b   = (const float*)d_in[13];
  float* out = (float*)d_out;

  char* ws = (char*)d_ws;
  unsigned short* YF  = (unsigned short*)(ws);           // 1024*128*128 bf16 = 33,554,432 B
  float*          Mws = (float*)(ws + 33554432);         // 32768 fp32    =    131,072 B
  // total ws use: 33,685,504 B

  k0_prepM<<<dim3(128), dim3(256), 0, stream>>>(out_w, fuse_w, Mws);
  k1_front<<<dim3(1024), dim3(256), 0, stream>>>(x, in_w, conv_w, conv_b, xp_w,
                                                 dtp_w, dtp_b, A_log, Dp, YF);
  k3_fuse<<<dim3(512), dim3(256), 0, stream>>>(YF, Mws, fuse_b, ln_g, ln_b, out);
}

// Round 3
// 326.726 us; speedup vs baseline: 1.6450x; 1.6450x over previous
//
#include <hip/hip_runtime.h>
#include <math.h>

// MambaBlock: 4-direction 2D selective scan + fuse + LN + SiLU
// B=2, H=W=128, D_MODEL=64, D_INNER=128, D_STATE=16, DT_RANK=4, D_CONV=4
//
// R3: occupancy restructure. R2's 155KB-LDS fused kernel ran 1 wave/SIMD ->
// 457us of exposed latency (VALUBusy 49%, Occupancy 11.8%). Now:
//  K1 (79,872B LDS, 2 blk/CU): gather -> in-proj -> conv -> xp-proj;
//     u/uc staged bf16 in LDS; z, uc, B/C, dt-rank rows spilled to ws.
//  K2 (no LDS, 2048 waves): selective scan, 1 thread/(n,d), yf written
//     in-place over z (thread-exclusive ownership).
//  K3 (70,656B LDS, 2 blk/CU): 4 passes (1 dir each), GEMM vs folded M,
//     LN + SiLU + store.

__device__ __forceinline__ unsigned short f2bf(float f) {
  unsigned int u = __float_as_uint(f);
  u += 0x7fffu + ((u >> 16) & 1u);
  return (unsigned short)(u >> 16);
}
__device__ __forceinline__ float bf2f(unsigned short h) {
  return __uint_as_float(((unsigned int)h) << 16);
}
__device__ __forceinline__ float siluf(float x) { return x / (1.f + __expf(-x)); }

// ---------------------------------------------------------------- K0
__global__ void k0_prepM(const float* __restrict__ out_w, const float* __restrict__ fuse_w,
                         float* __restrict__ M) {
  int idx = blockIdx.x * 256 + threadIdx.x;   // 4*128*64 = 32768
  int o = idx & 63;
  int d = (idx >> 6) & 127;
  int dir = idx >> 13;
  float acc = 0.f;
  #pragma unroll 8
  for (int j = 0; j < 64; ++j)
    acc += out_w[(dir*64 + j)*128 + d] * fuse_w[o*256 + dir*64 + j];
  M[idx] = acc;   // layout [dir][d][o]
}

// ---------------------------------------------------------------- K1
// LDS (79,872 B total -> 2 blocks/CU):
//   sx   @0      32768B  fp32 [64][128] x tile; phase4: sXW fp32 [36][132] (19008B)
//   sUC  @32768  34816B  u16  [128][136] u_pre -> uc (bf16)
//   region C @67584 (12288B): phase2 sW fp32[4][256] (4096B);
//                             phase4 sBC u16[128][40] (10240B) + sDT fp32[128][4] (2048B)
__global__ __launch_bounds__(256, 2) void k1_front(
    const float* __restrict__ x, const float* __restrict__ in_w,
    const float* __restrict__ conv_w, const float* __restrict__ conv_b,
    const float* __restrict__ xp_w,
    unsigned short* __restrict__ UC, unsigned short* __restrict__ ZY,
    unsigned short* __restrict__ BCg, float* __restrict__ DTRg)
{
  __shared__ __align__(16) char smem[79872];
  float* sx          = (float*)smem;                      // 8192 floats
  unsigned short* sUC= (unsigned short*)(smem + 32768);   // [128][136]
  float* sW          = (float*)(smem + 67584);            // 1024 floats (phase 2)
  unsigned short* sBC= (unsigned short*)(smem + 67584);   // [128][40]  (phase 4)
  float* sDT         = (float*)(smem + 67584 + 10240);    // [128][4]   (phase 4)

  const int tid = threadIdx.x;
  const int dir = blockIdx.x >> 8;
  const int n   = blockIdx.x & 255;
  const int b   = n >> 7;
  const int r   = n & 127;
  const float* xb = x + (size_t)b * (64*128*128);
  const int n_all = dir*256 + n;

  // ---- phase 1: gather tokens into sx[c][l] ----
  if (dir == 0) {
    for (int f = tid*4; f < 8192; f += 1024) {
      int c = f >> 7, l = f & 127;
      float4 v = *(const float4*)(xb + ((size_t)c*128 + r)*128 + l);
      *(float4*)(sx + c*128 + l) = v;
    }
  } else if (dir == 1) {
    for (int f = tid*4; f < 8192; f += 1024) {
      int c = f >> 7, w = f & 127;
      float4 v = *(const float4*)(xb + ((size_t)c*128 + r)*128 + w);
      float* row = sx + c*128;
      row[127-w] = v.x; row[126-w] = v.y; row[125-w] = v.z; row[124-w] = v.w;
    }
  } else if (dir == 2) {
    for (int f = tid; f < 8192; f += 256) {
      int c = f >> 7, l = f & 127;
      sx[c*128 + l] = xb[((size_t)c*128 + l)*128 + r];
    }
  } else {
    for (int f = tid; f < 8192; f += 256) {
      int c = f >> 7, l = f & 127;
      sx[c*128 + l] = xb[((size_t)c*128 + (127-l))*128 + r];
    }
  }
  __syncthreads();

  // ---- phase 2: in-projection (u rows 0..127 -> sUC bf16, z rows -> global bf16) ----
  const float* w_in = in_w + (size_t)dir * (256*64);
  const int dgrp = tid >> 3;     // 0..31 -> d0 = dgrp*8
  const int lgrp = tid & 7;      // l = lgrp*4 + ii*32 + q
  const int d0 = dgrp * 8;

  float acc[16][8];
  #pragma unroll
  for (int i = 0; i < 16; ++i)
    #pragma unroll
    for (int jj = 0; jj < 8; ++jj) acc[i][jj] = 0.f;

  for (int c0 = 0; c0 < 64; c0 += 4) {
    __syncthreads();
    {
      float4 wv = *(const float4*)(w_in + tid*64 + c0);
      sW[tid] = wv.x; sW[256+tid] = wv.y; sW[512+tid] = wv.z; sW[768+tid] = wv.w;
    }
    __syncthreads();
    #pragma unroll
    for (int j = 0; j < 4; ++j) {
      float wreg[8];
      #pragma unroll
      for (int dd = 0; dd < 8; ++dd) wreg[dd] = sW[j*256 + d0 + dd];
      #pragma unroll
      for (int ii = 0; ii < 4; ++ii) {
        float4 av = *(const float4*)(sx + (c0+j)*128 + lgrp*4 + ii*32);
        #pragma unroll
        for (int dd = 0; dd < 8; ++dd) {
          acc[ii*4+0][dd] += av.x * wreg[dd];
          acc[ii*4+1][dd] += av.y * wreg[dd];
          acc[ii*4+2][dd] += av.z * wreg[dd];
          acc[ii*4+3][dd] += av.w * wreg[dd];
        }
      }
    }
  }

  if (d0 < 128) {
    // u half -> sUC bf16 (packed uint4 = 8 bf16)
    #pragma unroll
    for (int ii = 0; ii < 4; ++ii)
      #pragma unroll
      for (int q = 0; q < 4; ++q) {
        int l = lgrp*4 + ii*32 + q;
        unsigned int pk[4];
        #pragma unroll
        for (int p = 0; p < 4; ++p) {
          unsigned short lo = f2bf(acc[ii*4+q][p*2+0]);
          unsigned short hi = f2bf(acc[ii*4+q][p*2+1]);
          pk[p] = (unsigned int)lo | ((unsigned int)hi << 16);
        }
        uint4 u4; u4.x = pk[0]; u4.y = pk[1]; u4.z = pk[2]; u4.w = pk[3];
        *(uint4*)(sUC + (size_t)l*136 + d0) = u4;
      }
  } else {
    // z half -> silu -> global ZY bf16
    const int dz = d0 - 128;
    unsigned short* Zn = ZY + (size_t)n_all * (128*128);
    #pragma unroll
    for (int ii = 0; ii < 4; ++ii)
      #pragma unroll
      for (int q = 0; q < 4; ++q) {
        int l = lgrp*4 + ii*32 + q;
        unsigned int pk[4];
        #pragma unroll
        for (int p = 0; p < 4; ++p) {
          unsigned short lo = f2bf(siluf(acc[ii*4+q][p*2+0]));
          unsigned short hi = f2bf(siluf(acc[ii*4+q][p*2+1]));
          pk[p] = (unsigned int)lo | ((unsigned int)hi << 16);
        }
        uint4 u4; u4.x = pk[0]; u4.y = pk[1]; u4.z = pk[2]; u4.w = pk[3];
        *(uint4*)(Zn + (size_t)l*128 + dz) = u4;
      }
  }
  __syncthreads();

  // ---- phase 3: causal conv-4 + silu in sUC (bf16) ----
  {
    const int d = tid & 127;
    const int half = tid >> 7;
    const int lc0 = half * 64;
    const float* cw = conv_w + (size_t)(dir*128 + d)*4;
    const float c0w = cw[0], c1w = cw[1], c2w = cw[2], c3w = cw[3];
    const float cb = conv_b[dir*128 + d];
    float p0 = half ? bf2f(sUC[(lc0-3)*136 + d]) : 0.f;
    float p1 = half ? bf2f(sUC[(lc0-2)*136 + d]) : 0.f;
    float p2 = half ? bf2f(sUC[(lc0-1)*136 + d]) : 0.f;
    __syncthreads();
    for (int l = lc0; l < lc0 + 64; ++l) {
      float cur = bf2f(sUC[l*136 + d]);
      float v = cb + c0w*p0 + c1w*p1 + c2w*p2 + c3w*cur;
      sUC[l*136 + d] = f2bf(siluf(v));
      p0 = p1; p1 = p2; p2 = cur;
    }
  }
  __syncthreads();

  // ---- phase 3.5: UC writeout + stage xp_w into sXW (disjoint LDS regions) ----
  {
    unsigned short* UCn = UC + (size_t)n_all * (128*128);
    for (int f = tid*8; f < 16384; f += 2048) {
      int l = f >> 7, dz = f & 127;
      uint4 v = *(const uint4*)(sUC + l*136 + dz);
      *(uint4*)(UCn + f) = v;
    }
    const float* wxp = xp_w + (size_t)dir * (36*128);
    float* sXW = sx;  // x no longer needed
    for (int f = tid; f < 36*128; f += 256) {
      int rr = f >> 7, dc = f & 127;
      sXW[rr*132 + dc] = wxp[f];
    }
  }
  __syncthreads();

  // ---- phase 4: xp projection; rows 0..3 -> sDT, rows 4..35 -> sBC ----
  {
    const float* sXW = sx;
    const int rgrp = tid & 3;
    const int lg = tid >> 2;          // tokens lg and lg+64
    const int r0 = rgrp * 9;
    float xa0[9], xa1[9];
    #pragma unroll
    for (int rr = 0; rr < 9; ++rr) { xa0[rr] = 0.f; xa1[rr] = 0.f; }
    for (int dq = 0; dq < 128; dq += 8) {
      uint4 u0 = *(const uint4*)(sUC + lg*136 + dq);
      uint4 u1 = *(const uint4*)(sUC + (lg+64)*136 + dq);
      float a0[8], a1[8];
      const unsigned int* pu0 = (const unsigned int*)&u0;
      const unsigned int* pu1 = (const unsigned int*)&u1;
      #pragma unroll
      for (int p = 0; p < 4; ++p) {
        a0[p*2+0] = __uint_as_float(pu0[p] << 16);
        a0[p*2+1] = __uint_as_float(pu0[p] & 0xffff0000u);
        a1[p*2+0] = __uint_as_float(pu1[p] << 16);
        a1[p*2+1] = __uint_as_float(pu1[p] & 0xffff0000u);
      }
      #pragma unroll
      for (int rr = 0; rr < 9; ++rr) {
        float4 w0 = *(const float4*)(sXW + (r0+rr)*132 + dq);
        float4 w1 = *(const float4*)(sXW + (r0+rr)*132 + dq + 4);
        xa0[rr] += a0[0]*w0.x + a0[1]*w0.y + a0[2]*w0.z + a0[3]*w0.w
                 + a0[4]*w1.x + a0[5]*w1.y + a0[6]*w1.z + a0[7]*w1.w;
        xa1[rr] += a1[0]*w0.x + a1[1]*w0.y + a1[2]*w0.z + a1[3]*w0.w
                 + a1[4]*w1.x + a1[5]*w1.y + a1[6]*w1.z + a1[7]*w1.w;
      }
    }
    // scatter rows into sDT (fp32, rows 0-3) / sBC (bf16, rows 4-35 -> cols 0-31)
    if (rgrp == 0) {
      float4 t0; t0.x = xa0[0]; t0.y = xa0[1]; t0.z = xa0[2]; t0.w = xa0[3];
      float4 t1; t1.x = xa1[0]; t1.y = xa1[1]; t1.z = xa1[2]; t1.w = xa1[3];
      *(float4*)(sDT + lg*4) = t0;
      *(float4*)(sDT + (lg+64)*4) = t1;
      #pragma unroll
      for (int rr = 4; rr < 9; ++rr) {
        sBC[lg*40 + (rr-4)] = f2bf(xa0[rr]);
        sBC[(lg+64)*40 + (rr-4)] = f2bf(xa1[rr]);
      }
    } else {
      #pragma unroll
      for (int rr = 0; rr < 9; ++rr) {
        int col = r0 + rr - 4;
        sBC[lg*40 + col] = f2bf(xa0[rr]);
        sBC[(lg+64)*40 + col] = f2bf(xa1[rr]);
      }
    }
  }
  __syncthreads();

  // ---- phase 5: cooperative writeout of sBC/sDT to global ----
  {
    unsigned short* BCn = BCg + (size_t)n_all * (128*32);
    for (int f = tid*8; f < 128*32; f += 2048) {
      int l = f >> 5, c = f & 31;
      uint4 v = *(const uint4*)(sBC + l*40 + c);
      *(uint4*)(BCn + f) = v;
    }
    float* DTn = DTRg + (size_t)n_all * (128*4);
    if (tid < 128) {
      float4 v = *(const float4*)(sDT + tid*4);
      *(float4*)(DTn + tid*4) = v;
    }
  }
}

// ---------------------------------------------------------------- K2 (scan)
__global__ __launch_bounds__(256) void k2_scan(
    const unsigned short* __restrict__ UC, unsigned short* __restrict__ ZY,
    const unsigned short* __restrict__ BCg, const float* __restrict__ DTRg,
    const float* __restrict__ dtp_w, const float* __restrict__ dtp_b,
    const float* __restrict__ A_log, const float* __restrict__ Dp)
{
  int g = blockIdx.x * 256 + threadIdx.x;     // 131072
  int d = g & 127;
  int n_all = g >> 7;                          // dir*256+n
  int dir = n_all >> 8;

  const float* dw = dtp_w + (size_t)(dir*128 + d) * 4;
  const float w0 = dw[0], w1 = dw[1], w2 = dw[2], w3 = dw[3];
  const float db = dtp_b[dir*128 + d];
  const float dpv = Dp[dir*128 + d];

  float Av[16];
  bool fast = true;
  #pragma unroll
  for (int s = 0; s < 16; ++s) {
    float a = -__expf(A_log[((size_t)(dir*128 + d))*16 + s]);
    Av[s] = a;
    if (fabsf((-a) - (float)(s+1)) > 1e-3f) fast = false;
  }

  const unsigned short* UCrow = UC + (size_t)n_all * (128*128) + d;
  unsigned short* Zrow        = ZY + (size_t)n_all * (128*128) + d;
  const unsigned short* BCn   = BCg + (size_t)n_all * (128*32);
  const float* DTn            = DTRg + (size_t)n_all * (128*4);

  float h[16];
  #pragma unroll
  for (int s = 0; s < 16; ++s) h[s] = 0.f;

  #define LOAD_BC_DT                                                        \
    float4 q0 = *(const float4*)(DTn + l*4);                                \
    float Bc[16], Cc[16];                                                   \
    {                                                                       \
      uint4 r0 = *(const uint4*)(BCn + l*32);                               \
      uint4 r1 = *(const uint4*)(BCn + l*32 + 8);                           \
      uint4 r2 = *(const uint4*)(BCn + l*32 + 16);                          \
      uint4 r3 = *(const uint4*)(BCn + l*32 + 24);                          \
      const unsigned int* p0 = (const unsigned int*)&r0;                    \
      const unsigned int* p1 = (const unsigned int*)&r1;                    \
      const unsigned int* p2 = (const unsigned int*)&r2;                    \
      const unsigned int* p3 = (const unsigned int*)&r3;                    \
      _Pragma("unroll")                                                     \
      for (int p = 0; p < 4; ++p) {                                         \
        Bc[p*2+0] = __uint_as_float(p0[p] << 16);                           \
        Bc[p*2+1] = __uint_as_float(p0[p] & 0xffff0000u);                   \
        Bc[8+p*2+0] = __uint_as_float(p1[p] << 16);                         \
        Bc[8+p*2+1] = __uint_as_float(p1[p] & 0xffff0000u);                 \
        Cc[p*2+0] = __uint_as_float(p2[p] << 16);                           \
        Cc[p*2+1] = __uint_as_float(p2[p] & 0xffff0000u);                   \
        Cc[8+p*2+0] = __uint_as_float(p3[p] << 16);                         \
        Cc[8+p*2+1] = __uint_as_float(p3[p] & 0xffff0000u);                 \
      }                                                                     \
    }                                                                       \
    float dr = q0.x*w0 + q0.y*w1 + q0.z*w2 + q0.w*w3 + db;                  \
    float dt = (dr > 20.f) ? dr : __logf(1.f + __expf(dr));                 \
    float u = bf2f(UCrow[(size_t)l*128]);                                   \
    float dtu = dt * u;

  if (fast) {
    for (int l = 0; l < 128; ++l) {
      LOAD_BC_DT
      float E = __expf(-dt);
      float e = 1.f;
      float y0 = 0.f, y1 = 0.f;
      #pragma unroll
      for (int s = 0; s < 16; s += 2) {
        e *= E; h[s]   = h[s]*e   + dtu*Bc[s];   y0 += h[s]*Cc[s];
        e *= E; h[s+1] = h[s+1]*e + dtu*Bc[s+1]; y1 += h[s+1]*Cc[s+1];
      }
      float z = bf2f(Zrow[(size_t)l*128]);
      Zrow[(size_t)l*128] = f2bf((y0 + y1 + u*dpv) * z);
    }
  } else {
    for (int l = 0; l < 128; ++l) {
      LOAD_BC_DT
      float y0 = 0.f, y1 = 0.f;
      #pragma unroll
      for (int s = 0; s < 16; s += 2) {
        float e0 = __expf(dt*Av[s]);   h[s]   = h[s]*e0   + dtu*Bc[s];   y0 += h[s]*Cc[s];
        float e1 = __expf(dt*Av[s+1]); h[s+1] = h[s+1]*e1 + dtu*Bc[s+1]; y1 += h[s+1]*Cc[s+1];
      }
      float z = bf2f(Zrow[(size_t)l*128]);
      Zrow[(size_t)l*128] = f2bf((y0 + y1 + u*dpv) * z);
    }
  }
  #undef LOAD_BC_DT
}

// ---------------------------------------------------------------- K3
// LDS 70,656B -> 2 blocks/CU. 4 passes, one direction each.
__global__ __launch_bounds__(256, 2) void k3_fuse(
    const unsigned short* __restrict__ YF, const float* __restrict__ M,
    const float* __restrict__ fuse_b, const float* __restrict__ ln_g,
    const float* __restrict__ ln_b, float* __restrict__ out)
{
  __shared__ __align__(16) char smem[70656];
  float* scy = (float*)smem;              // [64][132]
  float* sMT = (float*)(smem + 33792);    // [128][72]

  const int tid = threadIdx.x;
  const int blk = blockIdx.x;             // 512
  const int b = blk >> 8;
  const int rr2 = blk & 255;
  const int h = rr2 >> 1;
  const int w0 = (rr2 & 1) * 64;

  const int tokgrp = tid >> 3;            // 0..31 (toks tokgrp and tokgrp+32)
  const int ogrp = tid & 7;
  const int o0 = ogrp * 8;

  float acc[2][8];
  #pragma unroll
  for (int i = 0; i < 8; ++i) { acc[0][i] = 0.f; acc[1][i] = 0.f; }

  for (int dirg = 0; dirg < 4; ++dirg) {
    // stage M slice [128 d][64 o] -> sMT [128][72]
    for (int f = tid*4; f < 8192; f += 1024) {
      int j = f >> 6, o = f & 63;
      float4 v = *(const float4*)(M + (size_t)dirg*8192 + f);
      *(float4*)(sMT + j*72 + o) = v;
    }
    // gather this dir's yf for 64 tokens -> scy [64][132]
    for (int f = tid*8; f < 8192; f += 2048) {
      int tok = f >> 7;
      int dd = f & 127;
      size_t base;
      if      (dirg == 0) base = ((size_t)(0*256 + b*128 + h)*128 + (w0 + tok)) * 128;
      else if (dirg == 1) base = ((size_t)(1*256 + b*128 + h)*128 + (127 - w0 - tok)) * 128;
      else if (dirg == 2) base = ((size_t)(2*256 + b*128 + w0 + tok)*128 + h) * 128;
      else                base = ((size_t)(3*256 + b*128 + w0 + tok)*128 + (127 - h)) * 128;
      uint4 raw = *(const uint4*)(YF + base + dd);
      float* dst = scy + tok*132 + dd;
      dst[0] = __uint_as_float(raw.x << 16);
      dst[1] = __uint_as_float(raw.x & 0xffff0000u);
      dst[2] = __uint_as_float(raw.y << 16);
      dst[3] = __uint_as_float(raw.y & 0xffff0000u);
      dst[4] = __uint_as_float(raw.z << 16);
      dst[5] = __uint_as_float(raw.z & 0xffff0000u);
      dst[6] = __uint_as_float(raw.w << 16);
      dst[7] = __uint_as_float(raw.w & 0xffff0000u);
    }
    __syncthreads();
    const float* arow0 = scy + tokgrp*132;
    const float* arow1 = scy + (tokgrp+32)*132;
    for (int j0 = 0; j0 < 128; j0 += 4) {
      float4 a0 = *(const float4*)(arow0 + j0);
      float4 a1 = *(const float4*)(arow1 + j0);
      float aa0[4] = {a0.x, a0.y, a0.z, a0.w};
      float aa1[4] = {a1.x, a1.y, a1.z, a1.w};
      #pragma unroll
      for (int jj = 0; jj < 4; ++jj) {
        const float* wr = sMT + (j0+jj)*72 + o0;
        float4 wv0 = *(const float4*)(wr);
        float4 wv1 = *(const float4*)(wr + 4);
        float av0 = aa0[jj], av1 = aa1[jj];
        acc[0][0]+=av0*wv0.x; acc[0][1]+=av0*wv0.y; acc[0][2]+=av0*wv0.z; acc[0][3]+=av0*wv0.w;
        acc[0][4]+=av0*wv1.x; acc[0][5]+=av0*wv1.y; acc[0][6]+=av0*wv1.z; acc[0][7]+=av0*wv1.w;
        acc[1][0]+=av1*wv0.x; acc[1][1]+=av1*wv0.y; acc[1][2]+=av1*wv0.z; acc[1][3]+=av1*wv0.w;
        acc[1][4]+=av1*wv1.x; acc[1][5]+=av1*wv1.y; acc[1][6]+=av1*wv1.z; acc[1][7]+=av1*wv1.w;
      }
    }
    __syncthreads();
  }

  float fb[8], g8[8], bb[8];
  #pragma unroll
  for (int i = 0; i < 8; ++i) { fb[i]=fuse_b[o0+i]; g8[i]=ln_g[o0+i]; bb[i]=ln_b[o0+i]; }
  #pragma unroll
  for (int tt = 0; tt < 2; ++tt) {
    float fv[8]; float s1 = 0.f, s2 = 0.f;
    #pragma unroll
    for (int i = 0; i < 8; ++i) { float v = acc[tt][i] + fb[i]; fv[i] = v; s1 += v; s2 += v*v; }
    #pragma unroll
    for (int m = 1; m < 8; m <<= 1) { s1 += __shfl_xor(s1, m, 64); s2 += __shfl_xor(s2, m, 64); }
    float mu = s1 * (1.f/64.f);
    float var = s2 * (1.f/64.f) - mu*mu;
    float rs = rsqrtf(var + 1e-5f);
    int w = w0 + tokgrp + tt*32;
    #pragma unroll
    for (int i = 0; i < 8; ++i) {
      float v = (fv[i] - mu) * rs * g8[i] + bb[i];
      v = siluf(v);
      out[((size_t)(b*64 + o0 + i)*128 + h)*128 + w] = v;
    }
  }
}

// ---------------------------------------------------------------- host
extern "C" void kernel_launch(void* const* d_in, const int* in_sizes, int n_in,
                              void* d_out, int out_size, void* d_ws, size_t ws_size,
                              hipStream_t stream) {
  const float* x      = (const float*)d_in[0];
  const float* in_w   = (const float*)d_in[1];
  const float* conv_w = (const float*)d_in[2];
  const float* conv_b = (const float*)d_in[3];
  const float* xp_w   = (const float*)d_in[4];
  const float* dtp_w  = (const float*)d_in[5];
  const float* dtp_b  = (const float*)d_in[6];
  const float* A_log  = (const float*)d_in[7];
  const float* Dp     = (const float*)d_in[8];
  const float* out_w  = (const float*)d_in[9];
  const float* fuse_w = (const float*)d_in[10];
  const float* fuse_b = (const float*)d_in[11];
  const float* ln_g   = (const float*)d_in[12];
  const float* ln_b   = (const float*)d_in[13];
  float* out = (float*)d_out;

  // ws layout (BYTES, checked twice this time):
  char* ws = (char*)d_ws;
  unsigned short* UC  = (unsigned short*)(ws);              // 1024*128*128*2 = 33,554,432
  unsigned short* ZY  = (unsigned short*)(ws + 33554432);   // 33,554,432 (z, then yf in-place)
  unsigned short* BCg = (unsigned short*)(ws + 67108864);   // 1024*128*32*2 =  8,388,608
  float*          DTR = (float*)(ws + 75497472);            // 1024*128*4*4  =  2,097,152
  float*          Mws = (float*)(ws + 77594624);            //                   131,072
  // total 77,725,696 B

  k0_prepM<<<dim3(128), dim3(256), 0, stream>>>(out_w, fuse_w, Mws);
  k1_front<<<dim3(1024), dim3(256), 0, stream>>>(x, in_w, conv_w, conv_b, xp_w,
                                                 UC, ZY, BCg, DTR);
  k2_scan<<<dim3(512), dim3(256), 0, stream>>>(UC, ZY, BCg, DTR, dtp_w, dtp_b, A_log, Dp);
  k3_fuse<<<dim3(512), dim3(256), 0, stream>>>(ZY, Mws, fuse_b, ln_g, ln_b, out);
}

// Round 4
// 265.366 us; speedup vs baseline: 2.0254x; 1.2312x over previous
//
#include <hip/hip_runtime.h>
#include <math.h>

// MambaBlock: 4-direction 2D selective scan + fuse + LN + SiLU
// B=2, H=W=128, D_MODEL=64, D_INNER=128, D_STATE=16, DT_RANK=4, D_CONV=4
//
// R4: MFMA for k1's two GEMMs (in-proj, xp-proj). R3 post-mortem: k1 at 170us,
// VALUBusy 45%, MfmaUtil 0 -> ~76us of scalar-FMA issue doing matmul. Now:
//  K0: fold out_w*fuse_w -> M; convert in_w/xp_w to bf16 in ws (A-operands).
//  K1 (53,248B LDS -> 3 blk/CU): gather x->bf16 LDS; MFMA in-proj (A=in_w from
//     global bf16, B=x from LDS); conv4+silu in LDS; MFMA xp-proj (B=uc LDS).
//  K2: selective scan (unchanged).
//  K3: fuse GEMM + LN + SiLU (unchanged this round).

typedef __attribute__((ext_vector_type(8))) short short8;
typedef __attribute__((ext_vector_type(4))) float f32x4;

__device__ __forceinline__ unsigned short f2bf(float f) {
  unsigned int u = __float_as_uint(f);
  u += 0x7fffu + ((u >> 16) & 1u);
  return (unsigned short)(u >> 16);
}
__device__ __forceinline__ float bf2f(unsigned short h) {
  return __uint_as_float(((unsigned int)h) << 16);
}
__device__ __forceinline__ float siluf(float x) { return x / (1.f + __expf(-x)); }

// ---------------------------------------------------------------- K0
// blocks 0..127: fold M. blocks 128..159: in_w -> bf16. blocks 160..163: xp_w -> bf16 (pad 48 rows).
__global__ void k0_prep(const float* __restrict__ out_w, const float* __restrict__ fuse_w,
                        const float* __restrict__ in_w, const float* __restrict__ xp_w,
                        float* __restrict__ M, unsigned short* __restrict__ W16,
                        unsigned short* __restrict__ XW16) {
  int blk = blockIdx.x;
  int tid = threadIdx.x;
  if (blk < 128) {
    int idx = blk * 256 + tid;   // 4*128*64 = 32768
    int o = idx & 63;
    int d = (idx >> 6) & 127;
    int dir = idx >> 13;
    float acc = 0.f;
    #pragma unroll 8
    for (int j = 0; j < 64; ++j)
      acc += out_w[(dir*64 + j)*128 + d] * fuse_w[o*256 + dir*64 + j];
    M[idx] = acc;   // layout [dir][d][o]
  } else if (blk < 160) {
    int t = (blk - 128) * 256 + tid;        // 8192 threads, 8 elems each
    int base = t * 8;                        // 65536 total
    float4 v0 = *(const float4*)(in_w + base);
    float4 v1 = *(const float4*)(in_w + base + 4);
    uint4 pk;
    pk.x = (unsigned int)f2bf(v0.x) | ((unsigned int)f2bf(v0.y) << 16);
    pk.y = (unsigned int)f2bf(v0.z) | ((unsigned int)f2bf(v0.w) << 16);
    pk.z = (unsigned int)f2bf(v1.x) | ((unsigned int)f2bf(v1.y) << 16);
    pk.w = (unsigned int)f2bf(v1.z) | ((unsigned int)f2bf(v1.w) << 16);
    *(uint4*)(W16 + base) = pk;
  } else {
    int t = (blk - 160) * 256 + tid;        // 1024 threads
    for (int pid = t; pid < 4*48*128; pid += 1024) {
      int dir = pid / 6144;
      int rem = pid - dir*6144;
      int row = rem >> 7, c = rem & 127;
      XW16[pid] = (row < 36) ? f2bf(xp_w[dir*4608 + row*128 + c]) : (unsigned short)0;
    }
  }
}

// ---------------------------------------------------------------- K1
// LDS (53,248 B -> 3 blocks/CU):
//   sxb @0      18432B  bf16 [128 tok][72] x tile (c-contiguous)
//   sUC @18432  34816B  bf16 [128 tok][136] u_pre -> uc
__global__ __launch_bounds__(256, 3) void k1_front(
    const float* __restrict__ x,
    const unsigned short* __restrict__ W16, const unsigned short* __restrict__ XW16,
    const float* __restrict__ conv_w, const float* __restrict__ conv_b,
    unsigned short* __restrict__ UC, unsigned short* __restrict__ ZY,
    unsigned short* __restrict__ BCg, float* __restrict__ DTRg)
{
  __shared__ __align__(16) char smem[53248];
  unsigned short* sxb = (unsigned short*)smem;             // [128][72]
  unsigned short* sUC = (unsigned short*)(smem + 18432);   // [128][136]

  const int tid = threadIdx.x;
  const int dir = blockIdx.x >> 8;
  const int n   = blockIdx.x & 255;
  const int b   = n >> 7;
  const int r   = n & 127;
  const float* xb = x + (size_t)b * (64*128*128);
  const int n_all = dir*256 + n;

  // ---- phase 1: gather tokens into sxb[l][c] (bf16) ----
  if (dir == 0) {
    for (int f = tid*4; f < 8192; f += 1024) {
      int c = f >> 7, l = f & 127;
      float4 v = *(const float4*)(xb + ((size_t)c*128 + r)*128 + l);
      sxb[(l+0)*72 + c] = f2bf(v.x);
      sxb[(l+1)*72 + c] = f2bf(v.y);
      sxb[(l+2)*72 + c] = f2bf(v.z);
      sxb[(l+3)*72 + c] = f2bf(v.w);
    }
  } else if (dir == 1) {
    for (int f = tid*4; f < 8192; f += 1024) {
      int c = f >> 7, w = f & 127;
      float4 v = *(const float4*)(xb + ((size_t)c*128 + r)*128 + w);
      sxb[(127-w)*72 + c] = f2bf(v.x);
      sxb[(126-w)*72 + c] = f2bf(v.y);
      sxb[(125-w)*72 + c] = f2bf(v.z);
      sxb[(124-w)*72 + c] = f2bf(v.w);
    }
  } else if (dir == 2) {
    for (int f = tid; f < 8192; f += 256) {
      int c = f >> 7, l = f & 127;
      sxb[l*72 + c] = f2bf(xb[((size_t)c*128 + l)*128 + r]);
    }
  } else {
    for (int f = tid; f < 8192; f += 256) {
      int c = f >> 7, l = f & 127;
      sxb[l*72 + c] = f2bf(xb[((size_t)c*128 + (127-l))*128 + r]);
    }
  }
  __syncthreads();

  // ---- phase 2: MFMA in-projection. A=in_w[256][64] (global bf16), B=x (LDS). ----
  // Wave w owns token tiles {2w, 2w+1}; loops all 16 row-tiles.
  {
    const int wave = tid >> 6;
    const int lane = tid & 63;
    const int m16 = lane & 15;
    const int quad = lane >> 4;
    const int tb0 = wave * 32;

    short8 bf[2][2];
    #pragma unroll
    for (int tt = 0; tt < 2; ++tt)
      #pragma unroll
      for (int ks = 0; ks < 2; ++ks)
        bf[tt][ks] = *(const short8*)(sxb + (tb0 + tt*16 + m16)*72 + ks*32 + quad*8);

    const unsigned short* Wd = W16 + (size_t)dir * 16384;
    unsigned short* Zn = ZY + (size_t)n_all * 16384;

    for (int rt = 0; rt < 16; ++rt) {
      short8 af[2];
      #pragma unroll
      for (int ks = 0; ks < 2; ++ks)
        af[ks] = *(const short8*)(Wd + (rt*16 + m16)*64 + ks*32 + quad*8);
      #pragma unroll
      for (int tt = 0; tt < 2; ++tt) {
        f32x4 acc = {0.f, 0.f, 0.f, 0.f};
        acc = __builtin_amdgcn_mfma_f32_16x16x32_bf16(af[0], bf[tt][0], acc, 0, 0, 0);
        acc = __builtin_amdgcn_mfma_f32_16x16x32_bf16(af[1], bf[tt][1], acc, 0, 0, 0);
        const int tok = tb0 + tt*16 + m16;
        const int r0 = rt*16 + quad*4;
        if (rt < 8) {
          // u rows -> sUC packed 4 bf16 (8B)
          uint2 u2;
          u2.x = (unsigned int)f2bf(acc[0]) | ((unsigned int)f2bf(acc[1]) << 16);
          u2.y = (unsigned int)f2bf(acc[2]) | ((unsigned int)f2bf(acc[3]) << 16);
          *(uint2*)(sUC + tok*136 + r0) = u2;
        } else {
          // z rows -> silu -> global ZY (8B stores)
          uint2 u2;
          u2.x = (unsigned int)f2bf(siluf(acc[0])) | ((unsigned int)f2bf(siluf(acc[1])) << 16);
          u2.y = (unsigned int)f2bf(siluf(acc[2])) | ((unsigned int)f2bf(siluf(acc[3])) << 16);
          *(uint2*)(Zn + (size_t)tok*128 + (r0 - 128)) = u2;
        }
      }
    }
  }
  __syncthreads();

  // ---- phase 3: causal conv-4 + silu in sUC (bf16) ----
  {
    const int d = tid & 127;
    const int half = tid >> 7;
    const int lc0 = half * 64;
    const float* cw = conv_w + (size_t)(dir*128 + d)*4;
    const float c0w = cw[0], c1w = cw[1], c2w = cw[2], c3w = cw[3];
    const float cb = conv_b[dir*128 + d];
    float p0 = half ? bf2f(sUC[(lc0-3)*136 + d]) : 0.f;
    float p1 = half ? bf2f(sUC[(lc0-2)*136 + d]) : 0.f;
    float p2 = half ? bf2f(sUC[(lc0-1)*136 + d]) : 0.f;
    __syncthreads();
    for (int l = lc0; l < lc0 + 64; ++l) {
      float cur = bf2f(sUC[l*136 + d]);
      float v = cb + c0w*p0 + c1w*p1 + c2w*p2 + c3w*cur;
      sUC[l*136 + d] = f2bf(siluf(v));
      p0 = p1; p1 = p2; p2 = cur;
    }
  }
  __syncthreads();

  // ---- phase 3.5: UC writeout (coalesced uint4) ----
  {
    unsigned short* UCn = UC + (size_t)n_all * (128*128);
    for (int f = tid*8; f < 16384; f += 2048) {
      int l = f >> 7, dz = f & 127;
      uint4 v = *(const uint4*)(sUC + l*136 + dz);
      *(uint4*)(UCn + f) = v;
    }
  }

  // ---- phase 4: MFMA xp-projection. A=xp_w[48][128] (global bf16), B=uc (LDS). ----
  {
    const int wave = tid >> 6;
    const int lane = tid & 63;
    const int m16 = lane & 15;
    const int quad = lane >> 4;
    const int tb0 = wave * 32;

    short8 bf[2][4];
    #pragma unroll
    for (int tt = 0; tt < 2; ++tt)
      #pragma unroll
      for (int ks = 0; ks < 4; ++ks)
        bf[tt][ks] = *(const short8*)(sUC + (tb0 + tt*16 + m16)*136 + ks*32 + quad*8);

    const unsigned short* XWd = XW16 + (size_t)dir * (48*128);
    unsigned short* BCn = BCg + (size_t)n_all * (128*32);
    float* DTn = DTRg + (size_t)n_all * (128*4);

    for (int rt = 0; rt < 3; ++rt) {
      short8 af[4];
      #pragma unroll
      for (int ks = 0; ks < 4; ++ks)
        af[ks] = *(const short8*)(XWd + (rt*16 + m16)*128 + ks*32 + quad*8);
      #pragma unroll
      for (int tt = 0; tt < 2; ++tt) {
        f32x4 acc = {0.f, 0.f, 0.f, 0.f};
        #pragma unroll
        for (int ks = 0; ks < 4; ++ks)
          acc = __builtin_amdgcn_mfma_f32_16x16x32_bf16(af[ks], bf[tt][ks], acc, 0, 0, 0);
        const int tok = tb0 + tt*16 + m16;
        const int r0 = rt*16 + quad*4;   // xp row base: 0,4,...,44
        if (r0 == 0) {
          // dt-rank rows 0..3 -> fp32 DTR, coalesced float4
          float4 v; v.x = acc[0]; v.y = acc[1]; v.z = acc[2]; v.w = acc[3];
          *(float4*)(DTn + tok*4) = v;
        } else if (r0 < 36) {
          // B/C rows 4..35 -> bf16 BC cols 0..31 (8B stores)
          uint2 u2;
          u2.x = (unsigned int)f2bf(acc[0]) | ((unsigned int)f2bf(acc[1]) << 16);
          u2.y = (unsigned int)f2bf(acc[2]) | ((unsigned int)f2bf(acc[3]) << 16);
          *(uint2*)(BCn + tok*32 + (r0 - 4)) = u2;
        }
      }
    }
  }
}

// ---------------------------------------------------------------- K2 (scan)
__global__ __launch_bounds__(256) void k2_scan(
    const unsigned short* __restrict__ UC, unsigned short* __restrict__ ZY,
    const unsigned short* __restrict__ BCg, const float* __restrict__ DTRg,
    const float* __restrict__ dtp_w, const float* __restrict__ dtp_b,
    const float* __restrict__ A_log, const float* __restrict__ Dp)
{
  int g = blockIdx.x * 256 + threadIdx.x;     // 131072
  int d = g & 127;
  int n_all = g >> 7;                          // dir*256+n
  int dir = n_all >> 8;

  const float* dw = dtp_w + (size_t)(dir*128 + d) * 4;
  const float w0 = dw[0], w1 = dw[1], w2 = dw[2], w3 = dw[3];
  const float db = dtp_b[dir*128 + d];
  const float dpv = Dp[dir*128 + d];

  float Av[16];
  bool fast = true;
  #pragma unroll
  for (int s = 0; s < 16; ++s) {
    float a = -__expf(A_log[((size_t)(dir*128 + d))*16 + s]);
    Av[s] = a;
    if (fabsf((-a) - (float)(s+1)) > 1e-3f) fast = false;
  }

  const unsigned short* UCrow = UC + (size_t)n_all * (128*128) + d;
  unsigned short* Zrow        = ZY + (size_t)n_all * (128*128) + d;
  const unsigned short* BCn   = BCg + (size_t)n_all * (128*32);
  const float* DTn            = DTRg + (size_t)n_all * (128*4);

  float h[16];
  #pragma unroll
  for (int s = 0; s < 16; ++s) h[s] = 0.f;

  #define LOAD_BC_DT                                                        \
    float4 q0 = *(const float4*)(DTn + l*4);                                \
    float Bc[16], Cc[16];                                                   \
    {                                                                       \
      uint4 r0 = *(const uint4*)(BCn + l*32);                               \
      uint4 r1 = *(const uint4*)(BCn + l*32 + 8);                           \
      uint4 r2 = *(const uint4*)(BCn + l*32 + 16);                          \
      uint4 r3 = *(const uint4*)(BCn + l*32 + 24);                          \
      const unsigned int* p0 = (const unsigned int*)&r0;                    \
      const unsigned int* p1 = (const unsigned int*)&r1;                    \
      const unsigned int* p2 = (const unsigned int*)&r2;                    \
      const unsigned int* p3 = (const unsigned int*)&r3;                    \
      _Pragma("unroll")                                                     \
      for (int p = 0; p < 4; ++p) {                                         \
        Bc[p*2+0] = __uint_as_float(p0[p] << 16);                           \
        Bc[p*2+1] = __uint_as_float(p0[p] & 0xffff0000u);                   \
        Bc[8+p*2+0] = __uint_as_float(p1[p] << 16);                         \
        Bc[8+p*2+1] = __uint_as_float(p1[p] & 0xffff0000u);                 \
        Cc[p*2+0] = __uint_as_float(p2[p] << 16);                           \
        Cc[p*2+1] = __uint_as_float(p2[p] & 0xffff0000u);                   \
        Cc[8+p*2+0] = __uint_as_float(p3[p] << 16);                         \
        Cc[8+p*2+1] = __uint_as_float(p3[p] & 0xffff0000u);                 \
      }                                                                     \
    }                                                                       \
    float dr = q0.x*w0 + q0.y*w1 + q0.z*w2 + q0.w*w3 + db;                  \
    float dt = (dr > 20.f) ? dr : __logf(1.f + __expf(dr));                 \
    float u = bf2f(UCrow[(size_t)l*128]);                                   \
    float dtu = dt * u;

  if (fast) {
    for (int l = 0; l < 128; ++l) {
      LOAD_BC_DT
      float E = __expf(-dt);
      float e = 1.f;
      float y0 = 0.f, y1 = 0.f;
      #pragma unroll
      for (int s = 0; s < 16; s += 2) {
        e *= E; h[s]   = h[s]*e   + dtu*Bc[s];   y0 += h[s]*Cc[s];
        e *= E; h[s+1] = h[s+1]*e + dtu*Bc[s+1]; y1 += h[s+1]*Cc[s+1];
      }
      float z = bf2f(Zrow[(size_t)l*128]);
      Zrow[(size_t)l*128] = f2bf((y0 + y1 + u*dpv) * z);
    }
  } else {
    for (int l = 0; l < 128; ++l) {
      LOAD_BC_DT
      float y0 = 0.f, y1 = 0.f;
      #pragma unroll
      for (int s = 0; s < 16; s += 2) {
        float e0 = __expf(dt*Av[s]);   h[s]   = h[s]*e0   + dtu*Bc[s];   y0 += h[s]*Cc[s];
        float e1 = __expf(dt*Av[s+1]); h[s+1] = h[s+1]*e1 + dtu*Bc[s+1]; y1 += h[s+1]*Cc[s+1];
      }
      float z = bf2f(Zrow[(size_t)l*128]);
      Zrow[(size_t)l*128] = f2bf((y0 + y1 + u*dpv) * z);
    }
  }
  #undef LOAD_BC_DT
}

// ---------------------------------------------------------------- K3
// LDS 70,656B -> 2 blocks/CU. 4 passes, one direction each.
__global__ __launch_bounds__(256, 2) void k3_fuse(
    const unsigned short* __restrict__ YF, const float* __restrict__ M,
    const float* __restrict__ fuse_b, const float* __restrict__ ln_g,
    const float* __restrict__ ln_b, float* __restrict__ out)
{
  __shared__ __align__(16) char smem[70656];
  float* scy = (float*)smem;              // [64][132]
  float* sMT = (float*)(smem + 33792);    // [128][72]

  const int tid = threadIdx.x;
  const int blk = blockIdx.x;             // 512
  const int b = blk >> 8;
  const int rr2 = blk & 255;
  const int h = rr2 >> 1;
  const int w0 = (rr2 & 1) * 64;

  const int tokgrp = tid >> 3;            // 0..31 (toks tokgrp and tokgrp+32)
  const int ogrp = tid & 7;
  const int o0 = ogrp * 8;

  float acc[2][8];
  #pragma unroll
  for (int i = 0; i < 8; ++i) { acc[0][i] = 0.f; acc[1][i] = 0.f; }

  for (int dirg = 0; dirg < 4; ++dirg) {
    for (int f = tid*4; f < 8192; f += 1024) {
      int j = f >> 6, o = f & 63;
      float4 v = *(const float4*)(M + (size_t)dirg*8192 + f);
      *(float4*)(sMT + j*72 + o) = v;
    }
    for (int f = tid*8; f < 8192; f += 2048) {
      int tok = f >> 7;
      int dd = f & 127;
      size_t base;
      if      (dirg == 0) base = ((size_t)(0*256 + b*128 + h)*128 + (w0 + tok)) * 128;
      else if (dirg == 1) base = ((size_t)(1*256 + b*128 + h)*128 + (127 - w0 - tok)) * 128;
      else if (dirg == 2) base = ((size_t)(2*256 + b*128 + w0 + tok)*128 + h) * 128;
      else                base = ((size_t)(3*256 + b*128 + w0 + tok)*128 + (127 - h)) * 128;
      uint4 raw = *(const uint4*)(YF + base + dd);
      float* dst = scy + tok*132 + dd;
      dst[0] = __uint_as_float(raw.x << 16);
      dst[1] = __uint_as_float(raw.x & 0xffff0000u);
      dst[2] = __uint_as_float(raw.y << 16);
      dst[3] = __uint_as_float(raw.y & 0xffff0000u);
      dst[4] = __uint_as_float(raw.z << 16);
      dst[5] = __uint_as_float(raw.z & 0xffff0000u);
      dst[6] = __uint_as_float(raw.w << 16);
      dst[7] = __uint_as_float(raw.w & 0xffff0000u);
    }
    __syncthreads();
    const float* arow0 = scy + tokgrp*132;
    const float* arow1 = scy + (tokgrp+32)*132;
    for (int j0 = 0; j0 < 128; j0 += 4) {
      float4 a0 = *(const float4*)(arow0 + j0);
      float4 a1 = *(const float4*)(arow1 + j0);
      float aa0[4] = {a0.x, a0.y, a0.z, a0.w};
      float aa1[4] = {a1.x, a1.y, a1.z, a1.w};
      #pragma unroll
      for (int jj = 0; jj < 4; ++jj) {
        const float* wr = sMT + (j0+jj)*72 + o0;
        float4 wv0 = *(const float4*)(wr);
        float4 wv1 = *(const float4*)(wr + 4);
        float av0 = aa0[jj], av1 = aa1[jj];
        acc[0][0]+=av0*wv0.x; acc[0][1]+=av0*wv0.y; acc[0][2]+=av0*wv0.z; acc[0][3]+=av0*wv0.w;
        acc[0][4]+=av0*wv1.x; acc[0][5]+=av0*wv1.y; acc[0][6]+=av0*wv1.z; acc[0][7]+=av0*wv1.w;
        acc[1][0]+=av1*wv0.x; acc[1][1]+=av1*wv0.y; acc[1][2]+=av1*wv0.z; acc[1][3]+=av1*wv0.w;
        acc[1][4]+=av1*wv1.x; acc[1][5]+=av1*wv1.y; acc[1][6]+=av1*wv1.z; acc[1][7]+=av1*wv1.w;
      }
    }
    __syncthreads();
  }

  float fb[8], g8[8], bb[8];
  #pragma unroll
  for (int i = 0; i < 8; ++i) { fb[i]=fuse_b[o0+i]; g8[i]=ln_g[o0+i]; bb[i]=ln_b[o0+i]; }
  #pragma unroll
  for (int tt = 0; tt < 2; ++tt) {
    float fv[8]; float s1 = 0.f, s2 = 0.f;
    #pragma unroll
    for (int i = 0; i < 8; ++i) { float v = acc[tt][i] + fb[i]; fv[i] = v; s1 += v; s2 += v*v; }
    #pragma unroll
    for (int m = 1; m < 8; m <<= 1) { s1 += __shfl_xor(s1, m, 64); s2 += __shfl_xor(s2, m, 64); }
    float mu = s1 * (1.f/64.f);
    float var = s2 * (1.f/64.f) - mu*mu;
    float rs = rsqrtf(var + 1e-5f);
    int w = w0 + tokgrp + tt*32;
    #pragma unroll
    for (int i = 0; i < 8; ++i) {
      float v = (fv[i] - mu) * rs * g8[i] + bb[i];
      v = siluf(v);
      out[((size_t)(b*64 + o0 + i)*128 + h)*128 + w] = v;
    }
  }
}

// ---------------------------------------------------------------- host
extern "C" void kernel_launch(void* const* d_in, const int* in_sizes, int n_in,
                              void* d_out, int out_size, void* d_ws, size_t ws_size,
                              hipStream_t stream) {
  const float* x      = (const float*)d_in[0];
  const float* in_w   = (const float*)d_in[1];
  const float* conv_w = (const float*)d_in[2];
  const float* conv_b = (const float*)d_in[3];
  const float* xp_w   = (const float*)d_in[4];
  const float* dtp_w  = (const float*)d_in[5];
  const float* dtp_b  = (const float*)d_in[6];
  const float* A_log  = (const float*)d_in[7];
  const float* Dp     = (const float*)d_in[8];
  const float* out_w  = (const float*)d_in[9];
  const float* fuse_w = (const float*)d_in[10];
  const float* fuse_b = (const float*)d_in[11];
  const float* ln_g   = (const float*)d_in[12];
  const float* ln_b   = (const float*)d_in[13];
  float* out = (float*)d_out;

  // ws layout (BYTES):
  char* ws = (char*)d_ws;
  unsigned short* UC   = (unsigned short*)(ws);              // 33,554,432
  unsigned short* ZY   = (unsigned short*)(ws + 33554432);   // 33,554,432 (z, then yf in-place)
  unsigned short* BCg  = (unsigned short*)(ws + 67108864);   //  8,388,608
  float*          DTR  = (float*)(ws + 75497472);            //  2,097,152
  float*          Mws  = (float*)(ws + 77594624);            //    131,072
  unsigned short* W16  = (unsigned short*)(ws + 77725696);   //    131,072 (in_w bf16)
  unsigned short* XW16 = (unsigned short*)(ws + 77856768);   //     49,152 (xp_w bf16, 48-row pad)
  // total 77,905,920 B

  k0_prep<<<dim3(164), dim3(256), 0, stream>>>(out_w, fuse_w, in_w, xp_w, Mws, W16, XW16);
  k1_front<<<dim3(1024), dim3(256), 0, stream>>>(x, W16, XW16, conv_w, conv_b,
                                                 UC, ZY, BCg, DTR);
  k2_scan<<<dim3(512), dim3(256), 0, stream>>>(UC, ZY, BCg, DTR, dtp_w, dtp_b, A_log, Dp);
  k3_fuse<<<dim3(512), dim3(256), 0, stream>>>(ZY, Mws, fuse_b, ln_g, ln_b, out);
}

// Round 5
// 257.045 us; speedup vs baseline: 2.0910x; 1.0324x over previous
//
#include <hip/hip_runtime.h>
#include <math.h>

// MambaBlock: 4-direction 2D selective scan + fuse + LN + SiLU
// B=2, H=W=128, D_MODEL=64, D_INNER=128, D_STATE=16, DT_RANK=4, D_CONV=4
//
// R5: (a) scan fused back into k1 at 3 blk/CU (R2's fusion failed at 1 blk/CU;
// occupancy was the problem, not fusion) -> k2 deleted, UC/BC/DTR buffers gone.
// (b) k3 GEMM -> MFMA with bf16 M^T from k0 (gather needs no unpack: yf is bf16).
//
//  K0: MT16[o][dir*128+d] = bf16( sum_j out_w[dir][j][d]*fuse_w[o][dir*64+j] );
//      in_w -> W16 bf16; xp_w -> XW16 bf16 (48-row pad).
//  K1 (53,248B LDS, 3 blk/CU): gather -> MFMA in-proj -> conv4+silu ->
//      MFMA xp-proj (to LDS) -> scan (2 thr/channel) -> z-multiply -> ZY (yf bf16).
//  K3 (66,560B LDS, 2 blk/CU): gather 4-dir yf (bf16), MFMA vs MT16, LN, SiLU, store.

typedef __attribute__((ext_vector_type(8))) short short8;
typedef __attribute__((ext_vector_type(4))) float f32x4;

__device__ __forceinline__ unsigned short f2bf(float f) {
  unsigned int u = __float_as_uint(f);
  u += 0x7fffu + ((u >> 16) & 1u);
  return (unsigned short)(u >> 16);
}
__device__ __forceinline__ float bf2f(unsigned short h) {
  return __uint_as_float(((unsigned int)h) << 16);
}
__device__ __forceinline__ float siluf(float x) { return x / (1.f + __expf(-x)); }

// ---------------------------------------------------------------- K0
// blocks 0..127: fold -> MT16. 128..159: in_w -> W16. 160..163: xp_w -> XW16.
__global__ void k0_prep(const float* __restrict__ out_w, const float* __restrict__ fuse_w,
                        const float* __restrict__ in_w, const float* __restrict__ xp_w,
                        unsigned short* __restrict__ MT16, unsigned short* __restrict__ W16,
                        unsigned short* __restrict__ XW16) {
  int blk = blockIdx.x;
  int tid = threadIdx.x;
  if (blk < 128) {
    int idx = blk * 256 + tid;   // 32768
    int d   = idx & 127;
    int o   = (idx >> 7) & 63;
    int dir = idx >> 13;
    float acc = 0.f;
    #pragma unroll 8
    for (int j = 0; j < 64; ++j)
      acc += out_w[(dir*64 + j)*128 + d] * fuse_w[o*256 + dir*64 + j];
    MT16[o*512 + dir*128 + d] = f2bf(acc);   // M^T layout [o][j=dir*128+d]
  } else if (blk < 160) {
    int t = (blk - 128) * 256 + tid;
    int base = t * 8;                        // 65536 total
    float4 v0 = *(const float4*)(in_w + base);
    float4 v1 = *(const float4*)(in_w + base + 4);
    uint4 pk;
    pk.x = (unsigned int)f2bf(v0.x) | ((unsigned int)f2bf(v0.y) << 16);
    pk.y = (unsigned int)f2bf(v0.z) | ((unsigned int)f2bf(v0.w) << 16);
    pk.z = (unsigned int)f2bf(v1.x) | ((unsigned int)f2bf(v1.y) << 16);
    pk.w = (unsigned int)f2bf(v1.z) | ((unsigned int)f2bf(v1.w) << 16);
    *(uint4*)(W16 + base) = pk;
  } else {
    int t = (blk - 160) * 256 + tid;        // 1024 threads
    for (int pid = t; pid < 4*48*128; pid += 1024) {
      int dir = pid / 6144;
      int rem = pid - dir*6144;
      int row = rem >> 7, c = rem & 127;
      XW16[pid] = (row < 36) ? f2bf(xp_w[dir*4608 + row*128 + c]) : (unsigned short)0;
    }
  }
}

// ---------------------------------------------------------------- K1 (fully fused)
// LDS (53,248 B -> 3 blocks/CU):
//   region A @0     18432B: phase1-2 sxb bf16 [128 tok][72];
//                           phase4+  sBC bf16 [128 tok][40] (10240B) + sDT fp32 [128][4] (2048B)
//   sUC @18432      34816B: bf16 [128 tok][136]  u_pre -> uc -> scan result
__global__ __launch_bounds__(256, 3) void k1_front(
    const float* __restrict__ x,
    const unsigned short* __restrict__ W16, const unsigned short* __restrict__ XW16,
    const float* __restrict__ conv_w, const float* __restrict__ conv_b,
    const float* __restrict__ dtp_w, const float* __restrict__ dtp_b,
    const float* __restrict__ A_log, const float* __restrict__ Dp,
    unsigned short* __restrict__ ZY)
{
  __shared__ __align__(16) char smem[53248];
  unsigned short* sxb = (unsigned short*)smem;             // [128][72]
  unsigned short* sBC = (unsigned short*)smem;             // [128][40]  (phase 4+)
  float* sDT          = (float*)(smem + 10240);            // [128][4]   (phase 4+)
  unsigned short* sUC = (unsigned short*)(smem + 18432);   // [128][136]

  const int tid = threadIdx.x;
  const int dir = blockIdx.x >> 8;
  const int n   = blockIdx.x & 255;
  const int b   = n >> 7;
  const int r   = n & 127;
  const float* xb = x + (size_t)b * (64*128*128);
  const int n_all = dir*256 + n;
  unsigned short* Zn = ZY + (size_t)n_all * 16384;

  // ---- phase 1: gather tokens into sxb[l][c] (bf16) ----
  if (dir == 0) {
    for (int f = tid*4; f < 8192; f += 1024) {
      int c = f >> 7, l = f & 127;
      float4 v = *(const float4*)(xb + ((size_t)c*128 + r)*128 + l);
      sxb[(l+0)*72 + c] = f2bf(v.x);
      sxb[(l+1)*72 + c] = f2bf(v.y);
      sxb[(l+2)*72 + c] = f2bf(v.z);
      sxb[(l+3)*72 + c] = f2bf(v.w);
    }
  } else if (dir == 1) {
    for (int f = tid*4; f < 8192; f += 1024) {
      int c = f >> 7, w = f & 127;
      float4 v = *(const float4*)(xb + ((size_t)c*128 + r)*128 + w);
      sxb[(127-w)*72 + c] = f2bf(v.x);
      sxb[(126-w)*72 + c] = f2bf(v.y);
      sxb[(125-w)*72 + c] = f2bf(v.z);
      sxb[(124-w)*72 + c] = f2bf(v.w);
    }
  } else if (dir == 2) {
    for (int f = tid; f < 8192; f += 256) {
      int c = f >> 7, l = f & 127;
      sxb[l*72 + c] = f2bf(xb[((size_t)c*128 + l)*128 + r]);
    }
  } else {
    for (int f = tid; f < 8192; f += 256) {
      int c = f >> 7, l = f & 127;
      sxb[l*72 + c] = f2bf(xb[((size_t)c*128 + (127-l))*128 + r]);
    }
  }
  __syncthreads();

  // ---- phase 2: MFMA in-projection. A=in_w (global bf16), B=x (LDS). ----
  {
    const int wave = tid >> 6;
    const int lane = tid & 63;
    const int m16 = lane & 15;
    const int quad = lane >> 4;
    const int tb0 = wave * 32;

    short8 bfr[2][2];
    #pragma unroll
    for (int tt = 0; tt < 2; ++tt)
      #pragma unroll
      for (int ks = 0; ks < 2; ++ks)
        bfr[tt][ks] = *(const short8*)(sxb + (tb0 + tt*16 + m16)*72 + ks*32 + quad*8);

    const unsigned short* Wd = W16 + (size_t)dir * 16384;

    for (int rt = 0; rt < 16; ++rt) {
      short8 af[2];
      #pragma unroll
      for (int ks = 0; ks < 2; ++ks)
        af[ks] = *(const short8*)(Wd + (rt*16 + m16)*64 + ks*32 + quad*8);
      #pragma unroll
      for (int tt = 0; tt < 2; ++tt) {
        f32x4 acc = {0.f, 0.f, 0.f, 0.f};
        acc = __builtin_amdgcn_mfma_f32_16x16x32_bf16(af[0], bfr[tt][0], acc, 0, 0, 0);
        acc = __builtin_amdgcn_mfma_f32_16x16x32_bf16(af[1], bfr[tt][1], acc, 0, 0, 0);
        const int tok = tb0 + tt*16 + m16;
        const int r0 = rt*16 + quad*4;
        if (rt < 8) {
          uint2 u2;
          u2.x = (unsigned int)f2bf(acc[0]) | ((unsigned int)f2bf(acc[1]) << 16);
          u2.y = (unsigned int)f2bf(acc[2]) | ((unsigned int)f2bf(acc[3]) << 16);
          *(uint2*)(sUC + tok*136 + r0) = u2;
        } else {
          uint2 u2;
          u2.x = (unsigned int)f2bf(siluf(acc[0])) | ((unsigned int)f2bf(siluf(acc[1])) << 16);
          u2.y = (unsigned int)f2bf(siluf(acc[2])) | ((unsigned int)f2bf(siluf(acc[3])) << 16);
          *(uint2*)(Zn + (size_t)tok*128 + (r0 - 128)) = u2;
        }
      }
    }
  }
  __syncthreads();

  // ---- phase 3: causal conv-4 + silu in sUC (bf16) ----
  {
    const int d = tid & 127;
    const int half = tid >> 7;
    const int lc0 = half * 64;
    const float* cw = conv_w + (size_t)(dir*128 + d)*4;
    const float c0w = cw[0], c1w = cw[1], c2w = cw[2], c3w = cw[3];
    const float cb = conv_b[dir*128 + d];
    float p0 = half ? bf2f(sUC[(lc0-3)*136 + d]) : 0.f;
    float p1 = half ? bf2f(sUC[(lc0-2)*136 + d]) : 0.f;
    float p2 = half ? bf2f(sUC[(lc0-1)*136 + d]) : 0.f;
    __syncthreads();
    for (int l = lc0; l < lc0 + 64; ++l) {
      float cur = bf2f(sUC[l*136 + d]);
      float v = cb + c0w*p0 + c1w*p1 + c2w*p2 + c3w*cur;
      sUC[l*136 + d] = f2bf(siluf(v));
      p0 = p1; p1 = p2; p2 = cur;
    }
  }
  __syncthreads();

  // ---- phase 4: MFMA xp-projection. A=xp_w (global bf16), B=uc (LDS sUC).
  //      Results stay in LDS: dt-rank rows -> sDT (fp32), B/C rows -> sBC (bf16).
  {
    const int wave = tid >> 6;
    const int lane = tid & 63;
    const int m16 = lane & 15;
    const int quad = lane >> 4;
    const int tb0 = wave * 32;

    short8 bfr[2][4];
    #pragma unroll
    for (int tt = 0; tt < 2; ++tt)
      #pragma unroll
      for (int ks = 0; ks < 4; ++ks)
        bfr[tt][ks] = *(const short8*)(sUC + (tb0 + tt*16 + m16)*136 + ks*32 + quad*8);

    const unsigned short* XWd = XW16 + (size_t)dir * (48*128);

    for (int rt = 0; rt < 3; ++rt) {
      short8 af[4];
      #pragma unroll
      for (int ks = 0; ks < 4; ++ks)
        af[ks] = *(const short8*)(XWd + (rt*16 + m16)*128 + ks*32 + quad*8);
      #pragma unroll
      for (int tt = 0; tt < 2; ++tt) {
        f32x4 acc = {0.f, 0.f, 0.f, 0.f};
        #pragma unroll
        for (int ks = 0; ks < 4; ++ks)
          acc = __builtin_amdgcn_mfma_f32_16x16x32_bf16(af[ks], bfr[tt][ks], acc, 0, 0, 0);
        const int tok = tb0 + tt*16 + m16;
        const int r0 = rt*16 + quad*4;   // 0,4,...,44
        if (r0 == 0) {
          float4 v; v.x = acc[0]; v.y = acc[1]; v.z = acc[2]; v.w = acc[3];
          *(float4*)(sDT + tok*4) = v;
        } else if (r0 < 36) {
          uint2 u2;
          u2.x = (unsigned int)f2bf(acc[0]) | ((unsigned int)f2bf(acc[1]) << 16);
          u2.y = (unsigned int)f2bf(acc[2]) | ((unsigned int)f2bf(acc[3]) << 16);
          *(uint2*)(sBC + tok*40 + (r0 - 4)) = u2;   // B: cols 0..15, C: cols 16..31
        }
      }
    }
  }
  __syncthreads();

  // ---- phase 5: selective scan, 2 threads/channel (8 states each). ----
  //      Writes (y + u*Dp) bf16 into sUC (uc slot is dead after use).
  {
    const int d = tid >> 1;
    const int p = tid & 1;
    const float* dwp = dtp_w + (size_t)(dir*128 + d) * 4;
    const float dw0 = dwp[0], dw1 = dwp[1], dw2 = dwp[2], dw3 = dwp[3];
    const float db = dtp_b[dir*128 + d];
    const float dpv = Dp[dir*128 + d];

    float Av[8];
    bool fast = true;
    #pragma unroll
    for (int j = 0; j < 8; ++j) {
      float a = -__expf(A_log[((size_t)(dir*128 + d))*16 + p*8 + j]);
      Av[j] = a;
      if (fabsf((-a) - (float)(p*8 + j + 1)) > 1e-3f) fast = false;
    }

    float h[8];
    #pragma unroll
    for (int j = 0; j < 8; ++j) h[j] = 0.f;

    #define SCAN_LOAD                                                     \
      float4 q0 = *(const float4*)(sDT + l*4);                            \
      uint4 rb = *(const uint4*)(sBC + l*40 + p*8);                       \
      uint4 rc = *(const uint4*)(sBC + l*40 + 16 + p*8);                  \
      float Bv[8], Cv[8];                                                 \
      {                                                                   \
        const unsigned int* pb = (const unsigned int*)&rb;                \
        const unsigned int* pc = (const unsigned int*)&rc;                \
        _Pragma("unroll")                                                 \
        for (int q = 0; q < 4; ++q) {                                     \
          Bv[q*2+0] = __uint_as_float(pb[q] << 16);                       \
          Bv[q*2+1] = __uint_as_float(pb[q] & 0xffff0000u);               \
          Cv[q*2+0] = __uint_as_float(pc[q] << 16);                       \
          Cv[q*2+1] = __uint_as_float(pc[q] & 0xffff0000u);               \
        }                                                                 \
      }                                                                   \
      float dr = q0.x*dw0 + q0.y*dw1 + q0.z*dw2 + q0.w*dw3 + db;          \
      float dt = (dr > 20.f) ? dr : __logf(1.f + __expf(dr));             \
      float u = bf2f(sUC[l*136 + d]);                                     \
      float dtu = dt * u;

    if (fast) {
      for (int l = 0; l < 128; ++l) {
        SCAN_LOAD
        float E = __expf(-dt);
        float E2 = E*E, E4 = E2*E2, E8 = E4*E4;
        float e = p ? E8 : 1.f;
        float yp = 0.f;
        #pragma unroll
        for (int j = 0; j < 8; ++j) {
          e *= E;
          h[j] = h[j]*e + dtu*Bv[j];
          yp += h[j]*Cv[j];
        }
        float ysum = yp + __shfl_xor(yp, 1, 64);
        if (p == 0) sUC[l*136 + d] = f2bf(ysum + u*dpv);
      }
    } else {
      for (int l = 0; l < 128; ++l) {
        SCAN_LOAD
        float yp = 0.f;
        #pragma unroll
        for (int j = 0; j < 8; ++j) {
          float ej = __expf(dt*Av[j]);
          h[j] = h[j]*ej + dtu*Bv[j];
          yp += h[j]*Cv[j];
        }
        float ysum = yp + __shfl_xor(yp, 1, 64);
        if (p == 0) sUC[l*136 + d] = f2bf(ysum + u*dpv);
      }
    }
    #undef SCAN_LOAD
  }
  __syncthreads();

  // ---- phase 6: yf = scan_result * silu(z); vectorized, in-place over ZY ----
  for (int f = tid*8; f < 16384; f += 2048) {
    int l = f >> 7, dz = f & 127;
    uint4 yv = *(const uint4*)(sUC + l*136 + dz);
    uint4 zv = *(const uint4*)(Zn + f);
    const unsigned int* py = (const unsigned int*)&yv;
    const unsigned int* pz = (const unsigned int*)&zv;
    uint4 ov;
    unsigned int* po = (unsigned int*)&ov;
    #pragma unroll
    for (int q = 0; q < 4; ++q) {
      float ylo = __uint_as_float(py[q] << 16);
      float yhi = __uint_as_float(py[q] & 0xffff0000u);
      float zlo = __uint_as_float(pz[q] << 16);
      float zhi = __uint_as_float(pz[q] & 0xffff0000u);
      po[q] = (unsigned int)f2bf(ylo*zlo) | ((unsigned int)f2bf(yhi*zhi) << 16);
    }
    *(uint4*)(Zn + f) = ov;
  }
}

// ---------------------------------------------------------------- K3 (MFMA fuse + LN)
// LDS 66,560B -> 2 blocks/CU. out[tok][o] = sum_j yf[tok][j] * MT16[o][j], j=dir*128+d.
__global__ __launch_bounds__(256, 2) void k3_fuse(
    const unsigned short* __restrict__ YF, const unsigned short* __restrict__ MT16,
    const float* __restrict__ fuse_b, const float* __restrict__ ln_g,
    const float* __restrict__ ln_b, float* __restrict__ out)
{
  __shared__ __align__(16) unsigned short sYB[64*520];   // 66,560 B

  const int tid = threadIdx.x;
  const int blk = blockIdx.x;             // 512
  const int b = blk >> 8;
  const int rr2 = blk & 255;
  const int h = rr2 >> 1;
  const int w0 = (rr2 & 1) * 64;

  // gather 4 dirs x 64 tokens x 128 ch of yf (bf16, no unpack) -> sYB[tok][dir*128+dd]
  for (int f = tid*8; f < 32768; f += 2048) {
    int dirg = f >> 13;
    int rem = f & 8191;
    int tok = rem >> 7;
    int dd = rem & 127;
    size_t base;
    if      (dirg == 0) base = ((size_t)(0*256 + b*128 + h)*128 + (w0 + tok)) * 128;
    else if (dirg == 1) base = ((size_t)(1*256 + b*128 + h)*128 + (127 - w0 - tok)) * 128;
    else if (dirg == 2) base = ((size_t)(2*256 + b*128 + w0 + tok)*128 + h) * 128;
    else                base = ((size_t)(3*256 + b*128 + w0 + tok)*128 + (127 - h)) * 128;
    uint4 raw = *(const uint4*)(YF + base + dd);
    *(uint4*)(sYB + tok*520 + dirg*128 + dd) = raw;
  }
  __syncthreads();

  const int wave = tid >> 6;
  const int lane = tid & 63;
  const int m16 = lane & 15;
  const int quad = lane >> 4;
  const int tok = wave*16 + m16;          // wave owns one 16-token n-tile

  // preload B-fragments (16 K-tiles of 32)
  short8 bfr[16];
  #pragma unroll
  for (int jt = 0; jt < 16; ++jt)
    bfr[jt] = *(const short8*)(sYB + tok*520 + jt*32 + quad*8);

  float facc[4][4];
  #pragma unroll
  for (int mt = 0; mt < 4; ++mt) {
    f32x4 acc = {0.f, 0.f, 0.f, 0.f};
    #pragma unroll
    for (int jt = 0; jt < 16; ++jt) {
      short8 af = *(const short8*)(MT16 + (size_t)(mt*16 + m16)*512 + jt*32 + quad*8);
      acc = __builtin_amdgcn_mfma_f32_16x16x32_bf16(af, bfr[jt], acc, 0, 0, 0);
    }
    facc[mt][0] = acc[0]; facc[mt][1] = acc[1]; facc[mt][2] = acc[2]; facc[mt][3] = acc[3];
  }

  // LN over o (64 per token): lane holds o = mt*16 + quad*4 + r; reduce across quads.
  float fv[16];
  float s1 = 0.f, s2 = 0.f;
  #pragma unroll
  for (int mt = 0; mt < 4; ++mt)
    #pragma unroll
    for (int rr = 0; rr < 4; ++rr) {
      int o = mt*16 + quad*4 + rr;
      float v = facc[mt][rr] + fuse_b[o];
      fv[mt*4 + rr] = v;
      s1 += v; s2 += v*v;
    }
  s1 += __shfl_xor(s1, 16, 64); s1 += __shfl_xor(s1, 32, 64);
  s2 += __shfl_xor(s2, 16, 64); s2 += __shfl_xor(s2, 32, 64);
  float mu = s1 * (1.f/64.f);
  float var = s2 * (1.f/64.f) - mu*mu;
  float rs = rsqrtf(var + 1e-5f);

  #pragma unroll
  for (int mt = 0; mt < 4; ++mt)
    #pragma unroll
    for (int rr = 0; rr < 4; ++rr) {
      int o = mt*16 + quad*4 + rr;
      float v = (fv[mt*4 + rr] - mu) * rs * ln_g[o] + ln_b[o];
      out[((size_t)(b*64 + o)*128 + h)*128 + (w0 + tok)] = siluf(v);
    }
}

// ---------------------------------------------------------------- host
extern "C" void kernel_launch(void* const* d_in, const int* in_sizes, int n_in,
                              void* d_out, int out_size, void* d_ws, size_t ws_size,
                              hipStream_t stream) {
  const float* x      = (const float*)d_in[0];
  const float* in_w   = (const float*)d_in[1];
  const float* conv_w = (const float*)d_in[2];
  const float* conv_b = (const float*)d_in[3];
  const float* xp_w   = (const float*)d_in[4];
  const float* dtp_w  = (const float*)d_in[5];
  const float* dtp_b  = (const float*)d_in[6];
  const float* A_log  = (const float*)d_in[7];
  const float* Dp     = (const float*)d_in[8];
  const float* out_w  = (const float*)d_in[9];
  const float* fuse_w = (const float*)d_in[10];
  const float* fuse_b = (const float*)d_in[11];
  const float* ln_g   = (const float*)d_in[12];
  const float* ln_b   = (const float*)d_in[13];
  float* out = (float*)d_out;

  // ws layout (BYTES):
  char* ws = (char*)d_ws;
  unsigned short* ZY   = (unsigned short*)(ws);              // 33,554,432 (silu(z) -> yf in-place)
  unsigned short* MT16 = (unsigned short*)(ws + 33554432);   //     65,536 (folded M^T bf16 [64][512])
  unsigned short* W16  = (unsigned short*)(ws + 33619968);   //    131,072 (in_w bf16)
  unsigned short* XW16 = (unsigned short*)(ws + 33751040);   //     49,152 (xp_w bf16, 48-row pad)
  // total 33,800,192 B

  k0_prep<<<dim3(164), dim3(256), 0, stream>>>(out_w, fuse_w, in_w, xp_w, MT16, W16, XW16);
  k1_front<<<dim3(1024), dim3(256), 0, stream>>>(x, W16, XW16, conv_w, conv_b,
                                                 dtp_w, dtp_b, A_log, Dp, ZY);
  k3_fuse<<<dim3(512), dim3(256), 0, stream>>>(ZY, MT16, fuse_b, ln_g, ln_b, out);
}

// Round 6
// 243.668 us; speedup vs baseline: 2.2058x; 1.0549x over previous
//
#include <hip/hip_runtime.h>
#include <math.h>

// MambaBlock: 4-direction 2D selective scan + fuse + LN + SiLU
// B=2, H=W=128, D_MODEL=64, D_INNER=128, D_STATE=16, DT_RANK=4, D_CONV=4
//
// R6: (a) dir-2/3 YF stored TRANSPOSED [dir][b*128+h][w][d] -> k3's gather is
// contiguous for all 4 dirs (R5 post-mortem: k3 ~90us was gather-latency-bound,
// 256B chunks at 32KB stride; scatter moved to k1's store side where it doesn't
// stall). z gets its own per-seq scratch ZB. (b) scan B/C kept fp32 in LDS
// (dead sxb region), dt-rank rows in sUC cols 128..135 -> kills 16 unpack
// VALU/step in the serial scan.
//
//  K0: fold out_w*fuse_w -> MT16 (bf16 M^T [64][512]); in_w/xp_w -> bf16.
//  K1 (53,248B LDS, 3 blk/CU): gather -> MFMA in-proj -> conv4+silu ->
//      MFMA xp-proj (results to LDS fp32) -> scan (2 thr/channel) ->
//      z-multiply -> YF (dir-dependent layout).
//  K3 (66,560B LDS, 2 blk/CU): contiguous gather 4-dir yf, MFMA vs MT16,
//      LN + SiLU, store.

typedef __attribute__((ext_vector_type(8))) short short8;
typedef __attribute__((ext_vector_type(4))) float f32x4;

__device__ __forceinline__ unsigned short f2bf(float f) {
  unsigned int u = __float_as_uint(f);
  u += 0x7fffu + ((u >> 16) & 1u);
  return (unsigned short)(u >> 16);
}
__device__ __forceinline__ float bf2f(unsigned short h) {
  return __uint_as_float(((unsigned int)h) << 16);
}
__device__ __forceinline__ float siluf(float x) { return x / (1.f + __expf(-x)); }

// ---------------------------------------------------------------- K0
// blocks 0..127: fold -> MT16. 128..159: in_w -> W16. 160..163: xp_w -> XW16.
__global__ void k0_prep(const float* __restrict__ out_w, const float* __restrict__ fuse_w,
                        const float* __restrict__ in_w, const float* __restrict__ xp_w,
                        unsigned short* __restrict__ MT16, unsigned short* __restrict__ W16,
                        unsigned short* __restrict__ XW16) {
  int blk = blockIdx.x;
  int tid = threadIdx.x;
  if (blk < 128) {
    int idx = blk * 256 + tid;   // 32768
    int d   = idx & 127;
    int o   = (idx >> 7) & 63;
    int dir = idx >> 13;
    float acc = 0.f;
    #pragma unroll 8
    for (int j = 0; j < 64; ++j)
      acc += out_w[(dir*64 + j)*128 + d] * fuse_w[o*256 + dir*64 + j];
    MT16[o*512 + dir*128 + d] = f2bf(acc);   // M^T layout [o][j=dir*128+d]
  } else if (blk < 160) {
    int t = (blk - 128) * 256 + tid;
    int base = t * 8;                        // 65536 total
    float4 v0 = *(const float4*)(in_w + base);
    float4 v1 = *(const float4*)(in_w + base + 4);
    uint4 pk;
    pk.x = (unsigned int)f2bf(v0.x) | ((unsigned int)f2bf(v0.y) << 16);
    pk.y = (unsigned int)f2bf(v0.z) | ((unsigned int)f2bf(v0.w) << 16);
    pk.z = (unsigned int)f2bf(v1.x) | ((unsigned int)f2bf(v1.y) << 16);
    pk.w = (unsigned int)f2bf(v1.z) | ((unsigned int)f2bf(v1.w) << 16);
    *(uint4*)(W16 + base) = pk;
  } else {
    int t = (blk - 160) * 256 + tid;        // 1024 threads
    for (int pid = t; pid < 4*48*128; pid += 1024) {
      int dir = pid / 6144;
      int rem = pid - dir*6144;
      int row = rem >> 7, c = rem & 127;
      XW16[pid] = (row < 36) ? f2bf(xp_w[dir*4608 + row*128 + c]) : (unsigned short)0;
    }
  }
}

// ---------------------------------------------------------------- K1 (fully fused)
// LDS (53,248 B -> 3 blocks/CU):
//   region A @0     18432B: ph1-2 sxb bf16 [128 tok][72];
//                           ph4+  sBCf fp32 [128 tok][36] (B cols 0..15, C cols 16..31)
//   sUC @18432      34816B: bf16 [128 tok][136]; cols 0..127 = u_pre -> uc -> y;
//                           cols 128..135 (16B) = dt-rank float4 (ph4+)
__global__ __launch_bounds__(256, 3) void k1_front(
    const float* __restrict__ x,
    const unsigned short* __restrict__ W16, const unsigned short* __restrict__ XW16,
    const float* __restrict__ conv_w, const float* __restrict__ conv_b,
    const float* __restrict__ dtp_w, const float* __restrict__ dtp_b,
    const float* __restrict__ A_log, const float* __restrict__ Dp,
    unsigned short* __restrict__ ZB, unsigned short* __restrict__ YF)
{
  __shared__ __align__(16) char smem[53248];
  unsigned short* sxb = (unsigned short*)smem;             // [128][72]  (ph1-2)
  float* sBCf         = (float*)smem;                      // [128][36]  (ph4+)
  unsigned short* sUC = (unsigned short*)(smem + 18432);   // [128][136]

  const int tid = threadIdx.x;
  const int dir = blockIdx.x >> 8;
  const int n   = blockIdx.x & 255;
  const int b   = n >> 7;
  const int r   = n & 127;
  const float* xb = x + (size_t)b * (64*128*128);
  const int n_all = dir*256 + n;
  unsigned short* ZBn = ZB + (size_t)n_all * 16384;

  // ---- phase 1: gather tokens into sxb[l][c] (bf16) ----
  if (dir == 0) {
    for (int f = tid*4; f < 8192; f += 1024) {
      int c = f >> 7, l = f & 127;
      float4 v = *(const float4*)(xb + ((size_t)c*128 + r)*128 + l);
      sxb[(l+0)*72 + c] = f2bf(v.x);
      sxb[(l+1)*72 + c] = f2bf(v.y);
      sxb[(l+2)*72 + c] = f2bf(v.z);
      sxb[(l+3)*72 + c] = f2bf(v.w);
    }
  } else if (dir == 1) {
    for (int f = tid*4; f < 8192; f += 1024) {
      int c = f >> 7, w = f & 127;
      float4 v = *(const float4*)(xb + ((size_t)c*128 + r)*128 + w);
      sxb[(127-w)*72 + c] = f2bf(v.x);
      sxb[(126-w)*72 + c] = f2bf(v.y);
      sxb[(125-w)*72 + c] = f2bf(v.z);
      sxb[(124-w)*72 + c] = f2bf(v.w);
    }
  } else if (dir == 2) {
    for (int f = tid; f < 8192; f += 256) {
      int c = f >> 7, l = f & 127;
      sxb[l*72 + c] = f2bf(xb[((size_t)c*128 + l)*128 + r]);
    }
  } else {
    for (int f = tid; f < 8192; f += 256) {
      int c = f >> 7, l = f & 127;
      sxb[l*72 + c] = f2bf(xb[((size_t)c*128 + (127-l))*128 + r]);
    }
  }
  __syncthreads();

  // ---- phase 2: MFMA in-projection. A=in_w (global bf16), B=x (LDS). ----
  {
    const int wave = tid >> 6;
    const int lane = tid & 63;
    const int m16 = lane & 15;
    const int quad = lane >> 4;
    const int tb0 = wave * 32;

    short8 bfr[2][2];
    #pragma unroll
    for (int tt = 0; tt < 2; ++tt)
      #pragma unroll
      for (int ks = 0; ks < 2; ++ks)
        bfr[tt][ks] = *(const short8*)(sxb + (tb0 + tt*16 + m16)*72 + ks*32 + quad*8);

    const unsigned short* Wd = W16 + (size_t)dir * 16384;

    for (int rt = 0; rt < 16; ++rt) {
      short8 af[2];
      #pragma unroll
      for (int ks = 0; ks < 2; ++ks)
        af[ks] = *(const short8*)(Wd + (rt*16 + m16)*64 + ks*32 + quad*8);
      #pragma unroll
      for (int tt = 0; tt < 2; ++tt) {
        f32x4 acc = {0.f, 0.f, 0.f, 0.f};
        acc = __builtin_amdgcn_mfma_f32_16x16x32_bf16(af[0], bfr[tt][0], acc, 0, 0, 0);
        acc = __builtin_amdgcn_mfma_f32_16x16x32_bf16(af[1], bfr[tt][1], acc, 0, 0, 0);
        const int tok = tb0 + tt*16 + m16;
        const int r0 = rt*16 + quad*4;
        if (rt < 8) {
          uint2 u2;
          u2.x = (unsigned int)f2bf(acc[0]) | ((unsigned int)f2bf(acc[1]) << 16);
          u2.y = (unsigned int)f2bf(acc[2]) | ((unsigned int)f2bf(acc[3]) << 16);
          *(uint2*)(sUC + tok*136 + r0) = u2;
        } else {
          uint2 u2;
          u2.x = (unsigned int)f2bf(siluf(acc[0])) | ((unsigned int)f2bf(siluf(acc[1])) << 16);
          u2.y = (unsigned int)f2bf(siluf(acc[2])) | ((unsigned int)f2bf(siluf(acc[3])) << 16);
          *(uint2*)(ZBn + (size_t)tok*128 + (r0 - 128)) = u2;
        }
      }
    }
  }
  __syncthreads();

  // ---- phase 3: causal conv-4 + silu in sUC (bf16) ----
  {
    const int d = tid & 127;
    const int half = tid >> 7;
    const int lc0 = half * 64;
    const float* cw = conv_w + (size_t)(dir*128 + d)*4;
    const float c0w = cw[0], c1w = cw[1], c2w = cw[2], c3w = cw[3];
    const float cb = conv_b[dir*128 + d];
    float p0 = half ? bf2f(sUC[(lc0-3)*136 + d]) : 0.f;
    float p1 = half ? bf2f(sUC[(lc0-2)*136 + d]) : 0.f;
    float p2 = half ? bf2f(sUC[(lc0-1)*136 + d]) : 0.f;
    __syncthreads();
    for (int l = lc0; l < lc0 + 64; ++l) {
      float cur = bf2f(sUC[l*136 + d]);
      float v = cb + c0w*p0 + c1w*p1 + c2w*p2 + c3w*cur;
      sUC[l*136 + d] = f2bf(siluf(v));
      p0 = p1; p1 = p2; p2 = cur;
    }
  }
  __syncthreads();

  // ---- phase 4: MFMA xp-projection. A=xp_w (global bf16), B=uc (LDS sUC).
  //      dt-rank rows -> sUC cols 128..135 (float4); B/C rows -> sBCf (fp32).
  {
    const int wave = tid >> 6;
    const int lane = tid & 63;
    const int m16 = lane & 15;
    const int quad = lane >> 4;
    const int tb0 = wave * 32;

    short8 bfr[2][4];
    #pragma unroll
    for (int tt = 0; tt < 2; ++tt)
      #pragma unroll
      for (int ks = 0; ks < 4; ++ks)
        bfr[tt][ks] = *(const short8*)(sUC + (tb0 + tt*16 + m16)*136 + ks*32 + quad*8);

    const unsigned short* XWd = XW16 + (size_t)dir * (48*128);

    for (int rt = 0; rt < 3; ++rt) {
      short8 af[4];
      #pragma unroll
      for (int ks = 0; ks < 4; ++ks)
        af[ks] = *(const short8*)(XWd + (rt*16 + m16)*128 + ks*32 + quad*8);
      #pragma unroll
      for (int tt = 0; tt < 2; ++tt) {
        f32x4 acc = {0.f, 0.f, 0.f, 0.f};
        #pragma unroll
        for (int ks = 0; ks < 4; ++ks)
          acc = __builtin_amdgcn_mfma_f32_16x16x32_bf16(af[ks], bfr[tt][ks], acc, 0, 0, 0);
        const int tok = tb0 + tt*16 + m16;
        const int r0 = rt*16 + quad*4;   // 0,4,...,44
        if (r0 == 0) {
          float4 v; v.x = acc[0]; v.y = acc[1]; v.z = acc[2]; v.w = acc[3];
          *(float4*)(smem + 18432 + tok*272 + 256) = v;      // sUC cols 128..135
        } else if (r0 < 36) {
          float4 v; v.x = acc[0]; v.y = acc[1]; v.z = acc[2]; v.w = acc[3];
          *(float4*)(sBCf + tok*36 + (r0 - 4)) = v;          // B: 0..15, C: 16..31
        }
      }
    }
  }
  __syncthreads();

  // ---- phase 5: selective scan, 2 threads/channel (8 states each). ----
  //      Writes (y + u*Dp) bf16 into sUC (uc slot dead after use).
  {
    const int d = tid >> 1;
    const int p = tid & 1;
    const float* dwp = dtp_w + (size_t)(dir*128 + d) * 4;
    const float dw0 = dwp[0], dw1 = dwp[1], dw2 = dwp[2], dw3 = dwp[3];
    const float db = dtp_b[dir*128 + d];
    const float dpv = Dp[dir*128 + d];

    float Av[8];
    bool fast = true;
    #pragma unroll
    for (int j = 0; j < 8; ++j) {
      float a = -__expf(A_log[((size_t)(dir*128 + d))*16 + p*8 + j]);
      Av[j] = a;
      if (fabsf((-a) - (float)(p*8 + j + 1)) > 1e-3f) fast = false;
    }

    float h[8];
    #pragma unroll
    for (int j = 0; j < 8; ++j) h[j] = 0.f;

    #define SCAN_LOAD                                                     \
      float4 q0 = *(const float4*)(smem + 18432 + l*272 + 256);           \
      float4 b0 = *(const float4*)(sBCf + l*36 + p*8);                    \
      float4 b1 = *(const float4*)(sBCf + l*36 + p*8 + 4);                \
      float4 c0 = *(const float4*)(sBCf + l*36 + 16 + p*8);               \
      float4 c1 = *(const float4*)(sBCf + l*36 + 16 + p*8 + 4);           \
      float Bv[8] = {b0.x,b0.y,b0.z,b0.w, b1.x,b1.y,b1.z,b1.w};           \
      float Cv[8] = {c0.x,c0.y,c0.z,c0.w, c1.x,c1.y,c1.z,c1.w};           \
      float dr = q0.x*dw0 + q0.y*dw1 + q0.z*dw2 + q0.w*dw3 + db;          \
      float dt = (dr > 20.f) ? dr : __logf(1.f + __expf(dr));             \
      float u = bf2f(sUC[l*136 + d]);                                     \
      float dtu = dt * u;

    if (fast) {
      for (int l = 0; l < 128; ++l) {
        SCAN_LOAD
        float E = __expf(-dt);
        float E2 = E*E, E4 = E2*E2, E8 = E4*E4;
        float e = p ? E8 : 1.f;
        float yp = 0.f;
        #pragma unroll
        for (int j = 0; j < 8; ++j) {
          e *= E;
          h[j] = h[j]*e + dtu*Bv[j];
          yp += h[j]*Cv[j];
        }
        float ysum = yp + __shfl_xor(yp, 1, 64);
        if (p == 0) sUC[l*136 + d] = f2bf(ysum + u*dpv);
      }
    } else {
      for (int l = 0; l < 128; ++l) {
        SCAN_LOAD
        float yp = 0.f;
        #pragma unroll
        for (int j = 0; j < 8; ++j) {
          float ej = __expf(dt*Av[j]);
          h[j] = h[j]*ej + dtu*Bv[j];
          yp += h[j]*Cv[j];
        }
        float ysum = yp + __shfl_xor(yp, 1, 64);
        if (p == 0) sUC[l*136 + d] = f2bf(ysum + u*dpv);
      }
    }
    #undef SCAN_LOAD
  }
  __syncthreads();

  // ---- phase 6: yf = scan_result * silu(z); write to YF in dir-dependent layout.
  //      dir 0/1: per-seq [dir][n][l][d] (coalesced).
  //      dir 2/3: transposed [dir][b*128+h][w][d] (256B-granule scattered STORES;
  //               makes k3's reads contiguous).
  for (int f = tid*8; f < 16384; f += 2048) {
    int l = f >> 7, dz = f & 127;
    uint4 yv = *(const uint4*)(sUC + l*136 + dz);
    uint4 zv = *(const uint4*)(ZBn + f);
    const unsigned int* py = (const unsigned int*)&yv;
    const unsigned int* pz = (const unsigned int*)&zv;
    uint4 ov;
    unsigned int* po = (unsigned int*)&ov;
    #pragma unroll
    for (int q = 0; q < 4; ++q) {
      float ylo = __uint_as_float(py[q] << 16);
      float yhi = __uint_as_float(py[q] & 0xffff0000u);
      float zlo = __uint_as_float(pz[q] << 16);
      float zhi = __uint_as_float(pz[q] & 0xffff0000u);
      po[q] = (unsigned int)f2bf(ylo*zlo) | ((unsigned int)f2bf(yhi*zhi) << 16);
    }
    size_t oaddr;
    if (dir < 2)       oaddr = ((size_t)n_all*128 + l)*128 + dz;
    else if (dir == 2) oaddr = ((size_t)(512 + b*128 + l)*128 + r)*128 + dz;
    else               oaddr = ((size_t)(768 + b*128 + (127-l))*128 + r)*128 + dz;
    *(uint4*)(YF + oaddr) = ov;
  }
}

// ---------------------------------------------------------------- K3 (MFMA fuse + LN)
// LDS 66,560B -> 2 blocks/CU. All 4 dirs' reads contiguous thanks to R6 layout.
__global__ __launch_bounds__(256, 2) void k3_fuse(
    const unsigned short* __restrict__ YF, const unsigned short* __restrict__ MT16,
    const float* __restrict__ fuse_b, const float* __restrict__ ln_g,
    const float* __restrict__ ln_b, float* __restrict__ out)
{
  __shared__ __align__(16) unsigned short sYB[64*520];   // 66,560 B

  const int tid = threadIdx.x;
  const int blk = blockIdx.x;             // 512
  const int b = blk >> 8;
  const int rr2 = blk & 255;
  const int h = rr2 >> 1;
  const int w0 = (rr2 & 1) * 64;

  // gather 4 dirs x 64 tokens x 128 ch of yf -> sYB[tok][dir*128+dd]
  for (int f = tid*8; f < 32768; f += 2048) {
    int dirg = f >> 13;
    int rem = f & 8191;
    int tok = rem >> 7;
    int dd = rem & 127;
    int X = (dirg == 1) ? (127 - w0 - tok) : (w0 + tok);
    size_t base = ((size_t)(dirg*256 + b*128 + h)*128 + X)*128 + dd;
    *(uint4*)(sYB + tok*520 + dirg*128 + dd) = *(const uint4*)(YF + base);
  }
  __syncthreads();

  const int wave = tid >> 6;
  const int lane = tid & 63;
  const int m16 = lane & 15;
  const int quad = lane >> 4;
  const int tok = wave*16 + m16;          // wave owns one 16-token n-tile

  // preload B-fragments (16 K-tiles of 32)
  short8 bfr[16];
  #pragma unroll
  for (int jt = 0; jt < 16; ++jt)
    bfr[jt] = *(const short8*)(sYB + tok*520 + jt*32 + quad*8);

  float facc[4][4];
  #pragma unroll
  for (int mt = 0; mt < 4; ++mt) {
    f32x4 acc = {0.f, 0.f, 0.f, 0.f};
    #pragma unroll
    for (int jt = 0; jt < 16; ++jt) {
      short8 af = *(const short8*)(MT16 + (size_t)(mt*16 + m16)*512 + jt*32 + quad*8);
      acc = __builtin_amdgcn_mfma_f32_16x16x32_bf16(af, bfr[jt], acc, 0, 0, 0);
    }
    facc[mt][0] = acc[0]; facc[mt][1] = acc[1]; facc[mt][2] = acc[2]; facc[mt][3] = acc[3];
  }

  // LN over o (64 per token): lane holds o = mt*16 + quad*4 + rr; reduce across quads.
  float fv[16];
  float s1 = 0.f, s2 = 0.f;
  #pragma unroll
  for (int mt = 0; mt < 4; ++mt)
    #pragma unroll
    for (int rr = 0; rr < 4; ++rr) {
      int o = mt*16 + quad*4 + rr;
      float v = facc[mt][rr] + fuse_b[o];
      fv[mt*4 + rr] = v;
      s1 += v; s2 += v*v;
    }
  s1 += __shfl_xor(s1, 16, 64); s1 += __shfl_xor(s1, 32, 64);
  s2 += __shfl_xor(s2, 16, 64); s2 += __shfl_xor(s2, 32, 64);
  float mu = s1 * (1.f/64.f);
  float var = s2 * (1.f/64.f) - mu*mu;
  float rs = rsqrtf(var + 1e-5f);

  #pragma unroll
  for (int mt = 0; mt < 4; ++mt)
    #pragma unroll
    for (int rr = 0; rr < 4; ++rr) {
      int o = mt*16 + quad*4 + rr;
      float v = (fv[mt*4 + rr] - mu) * rs * ln_g[o] + ln_b[o];
      out[((size_t)(b*64 + o)*128 + h)*128 + (w0 + tok)] = siluf(v);
    }
}

// ---------------------------------------------------------------- host
extern "C" void kernel_launch(void* const* d_in, const int* in_sizes, int n_in,
                              void* d_out, int out_size, void* d_ws, size_t ws_size,
                              hipStream_t stream) {
  const float* x      = (const float*)d_in[0];
  const float* in_w   = (const float*)d_in[1];
  const float* conv_w = (const float*)d_in[2];
  const float* conv_b = (const float*)d_in[3];
  const float* xp_w   = (const float*)d_in[4];
  const float* dtp_w  = (const float*)d_in[5];
  const float* dtp_b  = (const float*)d_in[6];
  const float* A_log  = (const float*)d_in[7];
  const float* Dp     = (const float*)d_in[8];
  const float* out_w  = (const float*)d_in[9];
  const float* fuse_w = (const float*)d_in[10];
  const float* fuse_b = (const float*)d_in[11];
  const float* ln_g   = (const float*)d_in[12];
  const float* ln_b   = (const float*)d_in[13];
  float* out = (float*)d_out;

  // ws layout (BYTES):
  char* ws = (char*)d_ws;
  unsigned short* ZB   = (unsigned short*)(ws);              // 33,554,432 (silu(z) scratch)
  unsigned short* YF   = (unsigned short*)(ws + 33554432);   // 33,554,432 (yf, dir-layouts)
  unsigned short* MT16 = (unsigned short*)(ws + 67108864);   //     65,536 (M^T bf16 [64][512])
  unsigned short* W16  = (unsigned short*)(ws + 67174400);   //    131,072 (in_w bf16)
  unsigned short* XW16 = (unsigned short*)(ws + 67305472);   //     49,152 (xp_w bf16, 48-row pad)
  // total 67,354,624 B

  k0_prep<<<dim3(164), dim3(256), 0, stream>>>(out_w, fuse_w, in_w, xp_w, MT16, W16, XW16);
  k1_front<<<dim3(1024), dim3(256), 0, stream>>>(x, W16, XW16, conv_w, conv_b,
                                                 dtp_w, dtp_b, A_log, Dp, ZB, YF);
  k3_fuse<<<dim3(512), dim3(256), 0, stream>>>(YF, MT16, fuse_b, ln_g, ln_b, out);
}

// Round 7
// 229.353 us; speedup vs baseline: 2.3434x; 1.0624x over previous
//
#include <hip/hip_runtime.h>
#include <math.h>

// MambaBlock: 4-direction 2D selective scan + fuse + LN + SiLU
// B=2, H=W=128, D_MODEL=64, D_INNER=128, D_STATE=16, DT_RANK=4, D_CONV=4
//
// R7: k1 diet. (a) phase-1 deleted: k0 emits channel-last bf16 copies
// xhwc16[b][h][w][c] and (via kT2) xwhc16[b][w][h][c]; phase-2 MFMA B-fragments
// load straight from global (8 contiguous bf16 = one fragment) for all 4 dirs
// (reversal is pure index math). Kills sxb scatter-writes + 32 scalar
// stride-512B loads/thread in dirs 2/3. (b) z lives in 32 packed VGPRs between
// in-proj and the final multiply -> ZB buffer + 67MB HBM round-trip deleted.
// R6 lesson: residual (total - k1) is invariant under k3 rewrites -> harness
// overhead + small kernels; all leverage is k1.
//
//  K0: fold out_w*fuse_w -> MT16; in_w/xp_w -> bf16; x -> xhwc16.
//  KT2: xwhc16 from xhwc16 (coalesced 128B-chunk strided copy).
//  K1 (53,248B LDS, 3 blk/CU): MFMA in-proj (B from global) -> conv4+silu ->
//      MFMA xp-proj (to LDS) -> scan (2 thr/channel, fp32 B/C) -> z-mul from
//      regs -> YF (dir-dependent layout).
//  K3 (66,560B LDS, 2 blk/CU): contiguous gather, MFMA vs MT16, LN, SiLU.

typedef __attribute__((ext_vector_type(8))) short short8;
typedef __attribute__((ext_vector_type(4))) float f32x4;

__device__ __forceinline__ unsigned short f2bf(float f) {
  unsigned int u = __float_as_uint(f);
  u += 0x7fffu + ((u >> 16) & 1u);
  return (unsigned short)(u >> 16);
}
__device__ __forceinline__ float bf2f(unsigned short h) {
  return __uint_as_float(((unsigned int)h) << 16);
}
__device__ __forceinline__ float siluf(float x) { return x / (1.f + __expf(-x)); }

// ---------------------------------------------------------------- K0
// blk 0..127: fold -> MT16. 128..159: in_w -> W16. 160..163: xp_w -> XW16.
// blk 164..419: x[b][c][h][w] -> xhwc16[b][h][w][c] (bf16), one block per (b,h).
__global__ void k0_prep(const float* __restrict__ out_w, const float* __restrict__ fuse_w,
                        const float* __restrict__ in_w, const float* __restrict__ xp_w,
                        const float* __restrict__ x,
                        unsigned short* __restrict__ MT16, unsigned short* __restrict__ W16,
                        unsigned short* __restrict__ XW16, unsigned short* __restrict__ XH) {
  __shared__ unsigned short sT[64*132];   // transpose stage (blk>=164 only)
  int blk = blockIdx.x;
  int tid = threadIdx.x;
  if (blk < 128) {
    int idx = blk * 256 + tid;   // 32768
    int d   = idx & 127;
    int o   = (idx >> 7) & 63;
    int dir = idx >> 13;
    float acc = 0.f;
    #pragma unroll 8
    for (int j = 0; j < 64; ++j)
      acc += out_w[(dir*64 + j)*128 + d] * fuse_w[o*256 + dir*64 + j];
    MT16[o*512 + dir*128 + d] = f2bf(acc);   // M^T layout [o][j=dir*128+d]
  } else if (blk < 160) {
    int t = (blk - 128) * 256 + tid;
    int base = t * 8;                        // 65536 total
    float4 v0 = *(const float4*)(in_w + base);
    float4 v1 = *(const float4*)(in_w + base + 4);
    uint4 pk;
    pk.x = (unsigned int)f2bf(v0.x) | ((unsigned int)f2bf(v0.y) << 16);
    pk.y = (unsigned int)f2bf(v0.z) | ((unsigned int)f2bf(v0.w) << 16);
    pk.z = (unsigned int)f2bf(v1.x) | ((unsigned int)f2bf(v1.y) << 16);
    pk.w = (unsigned int)f2bf(v1.z) | ((unsigned int)f2bf(v1.w) << 16);
    *(uint4*)(W16 + base) = pk;
  } else if (blk < 164) {
    int t = (blk - 160) * 256 + tid;        // 1024 threads
    for (int pid = t; pid < 4*48*128; pid += 1024) {
      int dir = pid / 6144;
      int rem = pid - dir*6144;
      int row = rem >> 7, c = rem & 127;
      XW16[pid] = (row < 36) ? f2bf(xp_w[dir*4608 + row*128 + c]) : (unsigned short)0;
    }
  } else {
    int idx = blk - 164;                    // 0..255
    int b = idx >> 7, h = idx & 127;
    for (int f = tid*4; f < 8192; f += 1024) {
      int c = f >> 7, w = f & 127;
      float4 v = *(const float4*)(x + (((size_t)(b*64 + c)*128 + h)*128 + w));
      sT[c*132 + w + 0] = f2bf(v.x);
      sT[c*132 + w + 1] = f2bf(v.y);
      sT[c*132 + w + 2] = f2bf(v.z);
      sT[c*132 + w + 3] = f2bf(v.w);
    }
    __syncthreads();
    for (int f = tid*8; f < 8192; f += 2048) {
      int w = f >> 6, c0 = f & 63;
      unsigned int pk[4];
      #pragma unroll
      for (int p = 0; p < 4; ++p) {
        unsigned int lo = sT[(c0 + p*2 + 0)*132 + w];
        unsigned int hi = sT[(c0 + p*2 + 1)*132 + w];
        pk[p] = lo | (hi << 16);
      }
      uint4 v; v.x = pk[0]; v.y = pk[1]; v.z = pk[2]; v.w = pk[3];
      *(uint4*)(XH + (((size_t)(b*128 + h)*128 + w)*64 + c0)) = v;
    }
  }
}

// ---------------------------------------------------------------- KT2
// xwhc16[b][w][h][c] = xhwc16[b][h][w][c]; 128B c-rows, coalesced both sides.
__global__ void kT2(const unsigned short* __restrict__ XH, unsigned short* __restrict__ XW) {
  int idx = blockIdx.x;         // 256: (b,h)
  int b = idx >> 7, h = idx & 127;
  int tid = threadIdx.x;
  const unsigned short* src = XH + ((size_t)(b*128 + h)*128)*64;
  for (int f = tid*8; f < 8192; f += 2048) {
    int w = f >> 6, c = f & 63;
    uint4 v = *(const uint4*)(src + f);
    *(uint4*)(XW + (((size_t)(b*128 + w)*128 + h)*64 + c)) = v;
  }
}

// ---------------------------------------------------------------- K1 (fused)
// LDS (53,248 B -> 3 blocks/CU):
//   sBCf @0     18432B fp32 [128 tok][36] (B cols 0..15, C cols 16..31) [ph4+]
//   sUC  @18432 34816B bf16 [128 tok][136]; cols 0..127 = u_pre -> uc -> y;
//                      cols 128..135 = dt-rank float4 [ph4+]
__global__ __launch_bounds__(256, 3) void k1_front(
    const unsigned short* __restrict__ XH, const unsigned short* __restrict__ XW,
    const unsigned short* __restrict__ W16, const unsigned short* __restrict__ XW16,
    const float* __restrict__ conv_w, const float* __restrict__ conv_b,
    const float* __restrict__ dtp_w, const float* __restrict__ dtp_b,
    const float* __restrict__ A_log, const float* __restrict__ Dp,
    unsigned short* __restrict__ YF)
{
  __shared__ __align__(16) char smem[53248];
  float* sBCf         = (float*)smem;                      // [128][36]  (ph4+)
  unsigned short* sUC = (unsigned short*)(smem + 18432);   // [128][136]

  const int tid = threadIdx.x;
  const int dir = blockIdx.x >> 8;
  const int n   = blockIdx.x & 255;
  const int b   = n >> 7;
  const int r   = n & 127;
  const int n_all = dir*256 + n;

  const unsigned short* xsrc = (dir < 2 ? XH : XW) + ((size_t)(b*128 + r)*128)*64;

  const int wave = tid >> 6;
  const int lane = tid & 63;
  const int m16 = lane & 15;
  const int quad = lane >> 4;
  const int tb0 = wave * 32;
  const int st0 = tb0 + m16;          // scan-order tokens owned (B-fragment rows)
  const int st1 = tb0 + 16 + m16;
  const int sp0 = (dir & 1) ? (127 - st0) : st0;   // spatial index in xsrc
  const int sp1 = (dir & 1) ? (127 - st1) : st1;

  unsigned int zpk[2][8][2];   // silu(z) bf16-packed: [tok-half][k][pair] (32 VGPRs)

  // ---- phase 2: MFMA in-projection. A=in_w (global bf16), B=x (global bf16). ----
  {
    short8 bfr[2][2];
    #pragma unroll
    for (int ks = 0; ks < 2; ++ks) {
      bfr[0][ks] = *(const short8*)(xsrc + sp0*64 + ks*32 + quad*8);
      bfr[1][ks] = *(const short8*)(xsrc + sp1*64 + ks*32 + quad*8);
    }
    const unsigned short* Wd = W16 + (size_t)dir * 16384;

    // u rows (rt 0..7)
    for (int rt = 0; rt < 8; ++rt) {
      short8 af[2];
      #pragma unroll
      for (int ks = 0; ks < 2; ++ks)
        af[ks] = *(const short8*)(Wd + (rt*16 + m16)*64 + ks*32 + quad*8);
      #pragma unroll
      for (int tt = 0; tt < 2; ++tt) {
        f32x4 acc = {0.f, 0.f, 0.f, 0.f};
        acc = __builtin_amdgcn_mfma_f32_16x16x32_bf16(af[0], bfr[tt][0], acc, 0, 0, 0);
        acc = __builtin_amdgcn_mfma_f32_16x16x32_bf16(af[1], bfr[tt][1], acc, 0, 0, 0);
        const int tok = tt ? st1 : st0;
        const int r0 = rt*16 + quad*4;
        uint2 u2;
        u2.x = (unsigned int)f2bf(acc[0]) | ((unsigned int)f2bf(acc[1]) << 16);
        u2.y = (unsigned int)f2bf(acc[2]) | ((unsigned int)f2bf(acc[3]) << 16);
        *(uint2*)(sUC + tok*136 + r0) = u2;
      }
    }
    // z rows (rt 8..15) -> registers
    #pragma unroll
    for (int k = 0; k < 8; ++k) {
      short8 af[2];
      #pragma unroll
      for (int ks = 0; ks < 2; ++ks)
        af[ks] = *(const short8*)(Wd + ((8+k)*16 + m16)*64 + ks*32 + quad*8);
      #pragma unroll
      for (int tt = 0; tt < 2; ++tt) {
        f32x4 acc = {0.f, 0.f, 0.f, 0.f};
        acc = __builtin_amdgcn_mfma_f32_16x16x32_bf16(af[0], bfr[tt][0], acc, 0, 0, 0);
        acc = __builtin_amdgcn_mfma_f32_16x16x32_bf16(af[1], bfr[tt][1], acc, 0, 0, 0);
        zpk[tt][k][0] = (unsigned int)f2bf(siluf(acc[0])) | ((unsigned int)f2bf(siluf(acc[1])) << 16);
        zpk[tt][k][1] = (unsigned int)f2bf(siluf(acc[2])) | ((unsigned int)f2bf(siluf(acc[3])) << 16);
      }
    }
  }
  __syncthreads();

  // ---- phase 3: causal conv-4 + silu in sUC (bf16) ----
  {
    const int d = tid & 127;
    const int half = tid >> 7;
    const int lc0 = half * 64;
    const float* cw = conv_w + (size_t)(dir*128 + d)*4;
    const float c0w = cw[0], c1w = cw[1], c2w = cw[2], c3w = cw[3];
    const float cb = conv_b[dir*128 + d];
    float p0 = half ? bf2f(sUC[(lc0-3)*136 + d]) : 0.f;
    float p1 = half ? bf2f(sUC[(lc0-2)*136 + d]) : 0.f;
    float p2 = half ? bf2f(sUC[(lc0-1)*136 + d]) : 0.f;
    __syncthreads();
    for (int l = lc0; l < lc0 + 64; ++l) {
      float cur = bf2f(sUC[l*136 + d]);
      float v = cb + c0w*p0 + c1w*p1 + c2w*p2 + c3w*cur;
      sUC[l*136 + d] = f2bf(siluf(v));
      p0 = p1; p1 = p2; p2 = cur;
    }
  }
  __syncthreads();

  // ---- phase 4: MFMA xp-projection. A=xp_w (global bf16), B=uc (LDS sUC).
  //      dt rows -> sUC cols 128..135 (float4); B/C rows -> sBCf (fp32).
  {
    short8 bfr[2][4];
    #pragma unroll
    for (int tt = 0; tt < 2; ++tt)
      #pragma unroll
      for (int ks = 0; ks < 4; ++ks)
        bfr[tt][ks] = *(const short8*)(sUC + (tt ? st1 : st0)*136 + ks*32 + quad*8);

    const unsigned short* XWd = XW16 + (size_t)dir * (48*128);

    for (int rt = 0; rt < 3; ++rt) {
      short8 af[4];
      #pragma unroll
      for (int ks = 0; ks < 4; ++ks)
        af[ks] = *(const short8*)(XWd + (rt*16 + m16)*128 + ks*32 + quad*8);
      #pragma unroll
      for (int tt = 0; tt < 2; ++tt) {
        f32x4 acc = {0.f, 0.f, 0.f, 0.f};
        #pragma unroll
        for (int ks = 0; ks < 4; ++ks)
          acc = __builtin_amdgcn_mfma_f32_16x16x32_bf16(af[ks], bfr[tt][ks], acc, 0, 0, 0);
        const int tok = tt ? st1 : st0;
        const int r0 = rt*16 + quad*4;   // 0,4,...,44
        if (r0 == 0) {
          float4 v; v.x = acc[0]; v.y = acc[1]; v.z = acc[2]; v.w = acc[3];
          *(float4*)(smem + 18432 + tok*272 + 256) = v;      // sUC cols 128..135
        } else if (r0 < 36) {
          float4 v; v.x = acc[0]; v.y = acc[1]; v.z = acc[2]; v.w = acc[3];
          *(float4*)(sBCf + tok*36 + (r0 - 4)) = v;          // B: 0..15, C: 16..31
        }
      }
    }
  }
  __syncthreads();

  // ---- phase 5: selective scan, 2 threads/channel (8 states each). ----
  {
    const int d = tid >> 1;
    const int p = tid & 1;
    const float* dwp = dtp_w + (size_t)(dir*128 + d) * 4;
    const float dw0 = dwp[0], dw1 = dwp[1], dw2 = dwp[2], dw3 = dwp[3];
    const float db = dtp_b[dir*128 + d];
    const float dpv = Dp[dir*128 + d];

    float Av[8];
    bool fast = true;
    #pragma unroll
    for (int j = 0; j < 8; ++j) {
      float a = -__expf(A_log[((size_t)(dir*128 + d))*16 + p*8 + j]);
      Av[j] = a;
      if (fabsf((-a) - (float)(p*8 + j + 1)) > 1e-3f) fast = false;
    }

    float h[8];
    #pragma unroll
    for (int j = 0; j < 8; ++j) h[j] = 0.f;

    #define SCAN_LOAD                                                     \
      float4 q0 = *(const float4*)(smem + 18432 + l*272 + 256);           \
      float4 b0 = *(const float4*)(sBCf + l*36 + p*8);                    \
      float4 b1 = *(const float4*)(sBCf + l*36 + p*8 + 4);                \
      float4 c0 = *(const float4*)(sBCf + l*36 + 16 + p*8);               \
      float4 c1 = *(const float4*)(sBCf + l*36 + 16 + p*8 + 4);           \
      float Bv[8] = {b0.x,b0.y,b0.z,b0.w, b1.x,b1.y,b1.z,b1.w};           \
      float Cv[8] = {c0.x,c0.y,c0.z,c0.w, c1.x,c1.y,c1.z,c1.w};           \
      float dr = q0.x*dw0 + q0.y*dw1 + q0.z*dw2 + q0.w*dw3 + db;          \
      float dt = (dr > 20.f) ? dr : __logf(1.f + __expf(dr));             \
      float u = bf2f(sUC[l*136 + d]);                                     \
      float dtu = dt * u;

    if (fast) {
      for (int l = 0; l < 128; ++l) {
        SCAN_LOAD
        float E = __expf(-dt);
        float E2 = E*E, E4 = E2*E2, E8 = E4*E4;
        float e = p ? E8 : 1.f;
        float yp = 0.f;
        #pragma unroll
        for (int j = 0; j < 8; ++j) {
          e *= E;
          h[j] = h[j]*e + dtu*Bv[j];
          yp += h[j]*Cv[j];
        }
        float ysum = yp + __shfl_xor(yp, 1, 64);
        if (p == 0) sUC[l*136 + d] = f2bf(ysum + u*dpv);
      }
    } else {
      for (int l = 0; l < 128; ++l) {
        SCAN_LOAD
        float yp = 0.f;
        #pragma unroll
        for (int j = 0; j < 8; ++j) {
          float ej = __expf(dt*Av[j]);
          h[j] = h[j]*ej + dtu*Bv[j];
          yp += h[j]*Cv[j];
        }
        float ysum = yp + __shfl_xor(yp, 1, 64);
        if (p == 0) sUC[l*136 + d] = f2bf(ysum + u*dpv);
      }
    }
    #undef SCAN_LOAD
  }
  __syncthreads();

  // ---- phase 6: yf = y * silu(z) from registers; dir-dependent YF layout.
  //      dir 0/1: [n_all][l][d]; dir 2/3: transposed [dir][b*128+h][w][d].
  #pragma unroll
  for (int tt = 0; tt < 2; ++tt) {
    const int st = tt ? st1 : st0;
    size_t rowbase;
    if (dir < 2)       rowbase = ((size_t)n_all*128 + st)*128;
    else if (dir == 2) rowbase = ((size_t)(512 + b*128 + st)*128 + r)*128;
    else               rowbase = ((size_t)(768 + b*128 + (127-st))*128 + r)*128;
    #pragma unroll
    for (int k = 0; k < 8; ++k) {
      const int dz = 16*k + quad*4;
      uint2 yv = *(const uint2*)(sUC + st*136 + dz);
      float y0 = __uint_as_float(yv.x << 16);
      float y1 = __uint_as_float(yv.x & 0xffff0000u);
      float y2 = __uint_as_float(yv.y << 16);
      float y3 = __uint_as_float(yv.y & 0xffff0000u);
      unsigned int z01 = zpk[tt][k][0], z23 = zpk[tt][k][1];
      float z0 = __uint_as_float(z01 << 16);
      float z1 = __uint_as_float(z01 & 0xffff0000u);
      float z2 = __uint_as_float(z23 << 16);
      float z3 = __uint_as_float(z23 & 0xffff0000u);
      uint2 ov;
      ov.x = (unsigned int)f2bf(y0*z0) | ((unsigned int)f2bf(y1*z1) << 16);
      ov.y = (unsigned int)f2bf(y2*z2) | ((unsigned int)f2bf(y3*z3) << 16);
      *(uint2*)(YF + rowbase + dz) = ov;
    }
  }
}

// ---------------------------------------------------------------- K3 (MFMA fuse + LN)
__global__ __launch_bounds__(256, 2) void k3_fuse(
    const unsigned short* __restrict__ YF, const unsigned short* __restrict__ MT16,
    const float* __restrict__ fuse_b, const float* __restrict__ ln_g,
    const float* __restrict__ ln_b, float* __restrict__ out)
{
  __shared__ __align__(16) unsigned short sYB[64*520];   // 66,560 B

  const int tid = threadIdx.x;
  const int blk = blockIdx.x;             // 512
  const int b = blk >> 8;
  const int rr2 = blk & 255;
  const int h = rr2 >> 1;
  const int w0 = (rr2 & 1) * 64;

  for (int f = tid*8; f < 32768; f += 2048) {
    int dirg = f >> 13;
    int rem = f & 8191;
    int tok = rem >> 7;
    int dd = rem & 127;
    int X = (dirg == 1) ? (127 - w0 - tok) : (w0 + tok);
    size_t base = ((size_t)(dirg*256 + b*128 + h)*128 + X)*128 + dd;
    *(uint4*)(sYB + tok*520 + dirg*128 + dd) = *(const uint4*)(YF + base);
  }
  __syncthreads();

  const int wave = tid >> 6;
  const int lane = tid & 63;
  const int m16 = lane & 15;
  const int quad = lane >> 4;
  const int tok = wave*16 + m16;

  short8 bfr[16];
  #pragma unroll
  for (int jt = 0; jt < 16; ++jt)
    bfr[jt] = *(const short8*)(sYB + tok*520 + jt*32 + quad*8);

  float facc[4][4];
  #pragma unroll
  for (int mt = 0; mt < 4; ++mt) {
    f32x4 acc = {0.f, 0.f, 0.f, 0.f};
    #pragma unroll
    for (int jt = 0; jt < 16; ++jt) {
      short8 af = *(const short8*)(MT16 + (size_t)(mt*16 + m16)*512 + jt*32 + quad*8);
      acc = __builtin_amdgcn_mfma_f32_16x16x32_bf16(af, bfr[jt], acc, 0, 0, 0);
    }
    facc[mt][0] = acc[0]; facc[mt][1] = acc[1]; facc[mt][2] = acc[2]; facc[mt][3] = acc[3];
  }

  float fv[16];
  float s1 = 0.f, s2 = 0.f;
  #pragma unroll
  for (int mt = 0; mt < 4; ++mt)
    #pragma unroll
    for (int rr = 0; rr < 4; ++rr) {
      int o = mt*16 + quad*4 + rr;
      float v = facc[mt][rr] + fuse_b[o];
      fv[mt*4 + rr] = v;
      s1 += v; s2 += v*v;
    }
  s1 += __shfl_xor(s1, 16, 64); s1 += __shfl_xor(s1, 32, 64);
  s2 += __shfl_xor(s2, 16, 64); s2 += __shfl_xor(s2, 32, 64);
  float mu = s1 * (1.f/64.f);
  float var = s2 * (1.f/64.f) - mu*mu;
  float rs = rsqrtf(var + 1e-5f);

  #pragma unroll
  for (int mt = 0; mt < 4; ++mt)
    #pragma unroll
    for (int rr = 0; rr < 4; ++rr) {
      int o = mt*16 + quad*4 + rr;
      float v = (fv[mt*4 + rr] - mu) * rs * ln_g[o] + ln_b[o];
      out[((size_t)(b*64 + o)*128 + h)*128 + (w0 + tok)] = siluf(v);
    }
}

// ---------------------------------------------------------------- host
extern "C" void kernel_launch(void* const* d_in, const int* in_sizes, int n_in,
                              void* d_out, int out_size, void* d_ws, size_t ws_size,
                              hipStream_t stream) {
  const float* x      = (const float*)d_in[0];
  const float* in_w   = (const float*)d_in[1];
  const float* conv_w = (const float*)d_in[2];
  const float* conv_b = (const float*)d_in[3];
  const float* xp_w   = (const float*)d_in[4];
  const float* dtp_w  = (const float*)d_in[5];
  const float* dtp_b  = (const float*)d_in[6];
  const float* A_log  = (const float*)d_in[7];
  const float* Dp     = (const float*)d_in[8];
  const float* out_w  = (const float*)d_in[9];
  const float* fuse_w = (const float*)d_in[10];
  const float* fuse_b = (const float*)d_in[11];
  const float* ln_g   = (const float*)d_in[12];
  const float* ln_b   = (const float*)d_in[13];
  float* out = (float*)d_out;

  // ws layout (BYTES):
  char* ws = (char*)d_ws;
  unsigned short* YF   = (unsigned short*)(ws);              // 33,554,432 (yf, dir-layouts)
  unsigned short* MT16 = (unsigned short*)(ws + 33554432);   //     65,536
  unsigned short* W16  = (unsigned short*)(ws + 33619968);   //    131,072
  unsigned short* XW16 = (unsigned short*)(ws + 33751040);   //     49,152
  unsigned short* XH   = (unsigned short*)(ws + 33800192);   //  4,194,304 (xhwc16)
  unsigned short* XWt  = (unsigned short*)(ws + 37994496);   //  4,194,304 (xwhc16)
  // total 42,188,800 B

  k0_prep<<<dim3(420), dim3(256), 0, stream>>>(out_w, fuse_w, in_w, xp_w, x,
                                               MT16, W16, XW16, XH);
  kT2<<<dim3(256), dim3(256), 0, stream>>>(XH, XWt);
  k1_front<<<dim3(1024), dim3(256), 0, stream>>>(XH, XWt, W16, XW16, conv_w, conv_b,
                                                 dtp_w, dtp_b, A_log, Dp, YF);
  k3_fuse<<<dim3(512), dim3(256), 0, stream>>>(YF, MT16, fuse_b, ln_g, ln_b, out);
}

// Round 9
// 213.644 us; speedup vs baseline: 2.5157x; 1.0735x over previous
//
#include <hip/hip_runtime.h>
#include <hip/hip_bf16.h>
#include <math.h>

// MambaBlock: 4-direction 2D selective scan + fuse + LN + SiLU
// B=2, H=W=128, D_MODEL=64, D_INNER=128, D_STATE=16, DT_RANK=4, D_CONV=4
//
// R9 = R8 with the compile fix: __hip_bfloat16{,2} are not trivially copyable
// on this ROCm -> __builtin_bit_cast rejected; use __builtin_memcpy instead.
// R8 theory (unchanged): k1 VALU diet. R7 showed VALUBusy 68% @123.7us = ~84us
// issue, ~3x source FMA count. (a) divides -> v_rcp_f32; (b) bf16 pack ->
// __float22bfloat162_rn (HW cvt_pk); (c) E = 1/(1+exp(dr)) identity; (d) conv
// 2-chunk interleave for ILP on the serial LDS chain.

typedef __attribute__((ext_vector_type(8))) short short8;
typedef __attribute__((ext_vector_type(4))) float f32x4;

__device__ __forceinline__ unsigned int pk2bf(float a, float b) {
  __hip_bfloat162 h = __float22bfloat162_rn(make_float2(a, b));
  unsigned int u;
  __builtin_memcpy(&u, &h, 4);
  return u;
}
__device__ __forceinline__ unsigned short f2bf(float f) {
  __hip_bfloat16 h = __float2bfloat16(f);
  unsigned short s;
  __builtin_memcpy(&s, &h, 2);
  return s;
}
__device__ __forceinline__ float bf2f(unsigned short h) {
  return __uint_as_float(((unsigned int)h) << 16);
}
__device__ __forceinline__ float fastrcp(float x) { return __builtin_amdgcn_rcpf(x); }
__device__ __forceinline__ float siluf(float x) { return x * fastrcp(1.f + __expf(-x)); }

// ---------------------------------------------------------------- K0
// blk 0..127: fold -> MT16. 128..159: in_w -> W16. 160..163: xp_w -> XW16.
// blk 164..419: x[b][c][h][w] -> xhwc16[b][h][w][c] (bf16), one block per (b,h).
__global__ void k0_prep(const float* __restrict__ out_w, const float* __restrict__ fuse_w,
                        const float* __restrict__ in_w, const float* __restrict__ xp_w,
                        const float* __restrict__ x,
                        unsigned short* __restrict__ MT16, unsigned short* __restrict__ W16,
                        unsigned short* __restrict__ XW16, unsigned short* __restrict__ XH) {
  __shared__ unsigned short sT[64*132];   // transpose stage (blk>=164 only)
  int blk = blockIdx.x;
  int tid = threadIdx.x;
  if (blk < 128) {
    int idx = blk * 256 + tid;   // 32768
    int d   = idx & 127;
    int o   = (idx >> 7) & 63;
    int dir = idx >> 13;
    float acc = 0.f;
    #pragma unroll 8
    for (int j = 0; j < 64; ++j)
      acc += out_w[(dir*64 + j)*128 + d] * fuse_w[o*256 + dir*64 + j];
    MT16[o*512 + dir*128 + d] = f2bf(acc);   // M^T layout [o][j=dir*128+d]
  } else if (blk < 160) {
    int t = (blk - 128) * 256 + tid;
    int base = t * 8;                        // 65536 total
    float4 v0 = *(const float4*)(in_w + base);
    float4 v1 = *(const float4*)(in_w + base + 4);
    uint4 pk;
    pk.x = pk2bf(v0.x, v0.y);
    pk.y = pk2bf(v0.z, v0.w);
    pk.z = pk2bf(v1.x, v1.y);
    pk.w = pk2bf(v1.z, v1.w);
    *(uint4*)(W16 + base) = pk;
  } else if (blk < 164) {
    int t = (blk - 160) * 256 + tid;        // 1024 threads
    for (int pid = t; pid < 4*48*128; pid += 1024) {
      int dir = pid / 6144;
      int rem = pid - dir*6144;
      int row = rem >> 7, c = rem & 127;
      XW16[pid] = (row < 36) ? f2bf(xp_w[dir*4608 + row*128 + c]) : (unsigned short)0;
    }
  } else {
    int idx = blk - 164;                    // 0..255
    int b = idx >> 7, h = idx & 127;
    for (int f = tid*4; f < 8192; f += 1024) {
      int c = f >> 7, w = f & 127;
      float4 v = *(const float4*)(x + (((size_t)(b*64 + c)*128 + h)*128 + w));
      sT[c*132 + w + 0] = f2bf(v.x);
      sT[c*132 + w + 1] = f2bf(v.y);
      sT[c*132 + w + 2] = f2bf(v.z);
      sT[c*132 + w + 3] = f2bf(v.w);
    }
    __syncthreads();
    for (int f = tid*8; f < 8192; f += 2048) {
      int w = f >> 6, c0 = f & 63;
      unsigned int pk[4];
      #pragma unroll
      for (int p = 0; p < 4; ++p) {
        unsigned int lo = sT[(c0 + p*2 + 0)*132 + w];
        unsigned int hi = sT[(c0 + p*2 + 1)*132 + w];
        pk[p] = lo | (hi << 16);
      }
      uint4 v; v.x = pk[0]; v.y = pk[1]; v.z = pk[2]; v.w = pk[3];
      *(uint4*)(XH + (((size_t)(b*128 + h)*128 + w)*64 + c0)) = v;
    }
  }
}

// ---------------------------------------------------------------- KT2
// xwhc16[b][w][h][c] = xhwc16[b][h][w][c]; 128B c-rows, coalesced both sides.
__global__ void kT2(const unsigned short* __restrict__ XH, unsigned short* __restrict__ XW) {
  int idx = blockIdx.x;         // 256: (b,h)
  int b = idx >> 7, h = idx & 127;
  int tid = threadIdx.x;
  const unsigned short* src = XH + ((size_t)(b*128 + h)*128)*64;
  for (int f = tid*8; f < 8192; f += 2048) {
    int w = f >> 6, c = f & 63;
    uint4 v = *(const uint4*)(src + f);
    *(uint4*)(XW + (((size_t)(b*128 + w)*128 + h)*64 + c)) = v;
  }
}

// ---------------------------------------------------------------- K1 (fused)
// LDS (53,248 B -> 3 blocks/CU):
//   sBCf @0     18432B fp32 [128 tok][36] (B cols 0..15, C cols 16..31) [ph4+]
//   sUC  @18432 34816B bf16 [128 tok][136]; cols 0..127 = u_pre -> uc -> y;
//                      cols 128..135 = dt-rank float4 [ph4+]
__global__ __launch_bounds__(256, 3) void k1_front(
    const unsigned short* __restrict__ XH, const unsigned short* __restrict__ XW,
    const unsigned short* __restrict__ W16, const unsigned short* __restrict__ XW16,
    const float* __restrict__ conv_w, const float* __restrict__ conv_b,
    const float* __restrict__ dtp_w, const float* __restrict__ dtp_b,
    const float* __restrict__ A_log, const float* __restrict__ Dp,
    unsigned short* __restrict__ YF)
{
  __shared__ __align__(16) char smem[53248];
  float* sBCf         = (float*)smem;                      // [128][36]  (ph4+)
  unsigned short* sUC = (unsigned short*)(smem + 18432);   // [128][136]

  const int tid = threadIdx.x;
  const int dir = blockIdx.x >> 8;
  const int n   = blockIdx.x & 255;
  const int b   = n >> 7;
  const int r   = n & 127;
  const int n_all = dir*256 + n;

  const unsigned short* xsrc = (dir < 2 ? XH : XW) + ((size_t)(b*128 + r)*128)*64;

  const int wave = tid >> 6;
  const int lane = tid & 63;
  const int m16 = lane & 15;
  const int quad = lane >> 4;
  const int tb0 = wave * 32;
  const int st0 = tb0 + m16;          // scan-order tokens owned (B-fragment rows)
  const int st1 = tb0 + 16 + m16;
  const int sp0 = (dir & 1) ? (127 - st0) : st0;   // spatial index in xsrc
  const int sp1 = (dir & 1) ? (127 - st1) : st1;

  unsigned int zpk[2][8][2];   // silu(z) bf16-packed: [tok-half][k][pair] (32 VGPRs)

  // ---- phase 2: MFMA in-projection. A=in_w (global bf16), B=x (global bf16). ----
  {
    short8 bfr[2][2];
    #pragma unroll
    for (int ks = 0; ks < 2; ++ks) {
      bfr[0][ks] = *(const short8*)(xsrc + sp0*64 + ks*32 + quad*8);
      bfr[1][ks] = *(const short8*)(xsrc + sp1*64 + ks*32 + quad*8);
    }
    const unsigned short* Wd = W16 + (size_t)dir * 16384;

    // u rows (rt 0..7)
    for (int rt = 0; rt < 8; ++rt) {
      short8 af[2];
      #pragma unroll
      for (int ks = 0; ks < 2; ++ks)
        af[ks] = *(const short8*)(Wd + (rt*16 + m16)*64 + ks*32 + quad*8);
      #pragma unroll
      for (int tt = 0; tt < 2; ++tt) {
        f32x4 acc = {0.f, 0.f, 0.f, 0.f};
        acc = __builtin_amdgcn_mfma_f32_16x16x32_bf16(af[0], bfr[tt][0], acc, 0, 0, 0);
        acc = __builtin_amdgcn_mfma_f32_16x16x32_bf16(af[1], bfr[tt][1], acc, 0, 0, 0);
        const int tok = tt ? st1 : st0;
        const int r0 = rt*16 + quad*4;
        uint2 u2;
        u2.x = pk2bf(acc[0], acc[1]);
        u2.y = pk2bf(acc[2], acc[3]);
        *(uint2*)(sUC + tok*136 + r0) = u2;
      }
    }
    // z rows (rt 8..15) -> registers
    #pragma unroll
    for (int k = 0; k < 8; ++k) {
      short8 af[2];
      #pragma unroll
      for (int ks = 0; ks < 2; ++ks)
        af[ks] = *(const short8*)(Wd + ((8+k)*16 + m16)*64 + ks*32 + quad*8);
      #pragma unroll
      for (int tt = 0; tt < 2; ++tt) {
        f32x4 acc = {0.f, 0.f, 0.f, 0.f};
        acc = __builtin_amdgcn_mfma_f32_16x16x32_bf16(af[0], bfr[tt][0], acc, 0, 0, 0);
        acc = __builtin_amdgcn_mfma_f32_16x16x32_bf16(af[1], bfr[tt][1], acc, 0, 0, 0);
        zpk[tt][k][0] = pk2bf(siluf(acc[0]), siluf(acc[1]));
        zpk[tt][k][1] = pk2bf(siluf(acc[2]), siluf(acc[3]));
      }
    }
  }
  __syncthreads();

  // ---- phase 3: causal conv-4 + silu in sUC (bf16). 4 chunks of 32 tokens;
  //      each thread interleaves 2 independent chunks for ILP on the serial chain.
  {
    const int d = tid & 127;
    const int half = tid >> 7;
    const int ca = half * 32;          // chunk A: 0 or 32
    const int cb2 = (half + 2) * 32;   // chunk B: 64 or 96
    const float* cw = conv_w + (size_t)(dir*128 + d)*4;
    const float c0w = cw[0], c1w = cw[1], c2w = cw[2], c3w = cw[3];
    const float cbv = conv_b[dir*128 + d];
    float a0 = half ? bf2f(sUC[(ca-3)*136 + d]) : 0.f;
    float a1 = half ? bf2f(sUC[(ca-2)*136 + d]) : 0.f;
    float a2 = half ? bf2f(sUC[(ca-1)*136 + d]) : 0.f;
    float b0 = bf2f(sUC[(cb2-3)*136 + d]);
    float b1 = bf2f(sUC[(cb2-2)*136 + d]);
    float b2 = bf2f(sUC[(cb2-1)*136 + d]);
    __syncthreads();
    for (int i = 0; i < 32; ++i) {
      float curA = bf2f(sUC[(ca+i)*136 + d]);
      float curB = bf2f(sUC[(cb2+i)*136 + d]);
      float vA = cbv + c0w*a0 + c1w*a1 + c2w*a2 + c3w*curA;
      float vB = cbv + c0w*b0 + c1w*b1 + c2w*b2 + c3w*curB;
      sUC[(ca+i)*136 + d]  = f2bf(siluf(vA));
      sUC[(cb2+i)*136 + d] = f2bf(siluf(vB));
      a0 = a1; a1 = a2; a2 = curA;
      b0 = b1; b1 = b2; b2 = curB;
    }
  }
  __syncthreads();

  // ---- phase 4: MFMA xp-projection. A=xp_w (global bf16), B=uc (LDS sUC).
  //      dt rows -> sUC cols 128..135 (float4); B/C rows -> sBCf (fp32).
  {
    short8 bfr[2][4];
    #pragma unroll
    for (int tt = 0; tt < 2; ++tt)
      #pragma unroll
      for (int ks = 0; ks < 4; ++ks)
        bfr[tt][ks] = *(const short8*)(sUC + (tt ? st1 : st0)*136 + ks*32 + quad*8);

    const unsigned short* XWd = XW16 + (size_t)dir * (48*128);

    for (int rt = 0; rt < 3; ++rt) {
      short8 af[4];
      #pragma unroll
      for (int ks = 0; ks < 4; ++ks)
        af[ks] = *(const short8*)(XWd + (rt*16 + m16)*128 + ks*32 + quad*8);
      #pragma unroll
      for (int tt = 0; tt < 2; ++tt) {
        f32x4 acc = {0.f, 0.f, 0.f, 0.f};
        #pragma unroll
        for (int ks = 0; ks < 4; ++ks)
          acc = __builtin_amdgcn_mfma_f32_16x16x32_bf16(af[ks], bfr[tt][ks], acc, 0, 0, 0);
        const int tok = tt ? st1 : st0;
        const int r0 = rt*16 + quad*4;   // 0,4,...,44
        if (r0 == 0) {
          float4 v; v.x = acc[0]; v.y = acc[1]; v.z = acc[2]; v.w = acc[3];
          *(float4*)(smem + 18432 + tok*272 + 256) = v;      // sUC cols 128..135
        } else if (r0 < 36) {
          float4 v; v.x = acc[0]; v.y = acc[1]; v.z = acc[2]; v.w = acc[3];
          *(float4*)(sBCf + tok*36 + (r0 - 4)) = v;          // B: 0..15, C: 16..31
        }
      }
    }
  }
  __syncthreads();

  // ---- phase 5: selective scan, 2 threads/channel (8 states each). ----
  {
    const int d = tid >> 1;
    const int p = tid & 1;
    const float* dwp = dtp_w + (size_t)(dir*128 + d) * 4;
    const float dw0 = dwp[0], dw1 = dwp[1], dw2 = dwp[2], dw3 = dwp[3];
    const float db = dtp_b[dir*128 + d];
    const float dpv = Dp[dir*128 + d];

    float Av[8];
    bool fast = true;
    #pragma unroll
    for (int j = 0; j < 8; ++j) {
      float a = -__expf(A_log[((size_t)(dir*128 + d))*16 + p*8 + j]);
      Av[j] = a;
      if (fabsf((-a) - (float)(p*8 + j + 1)) > 1e-3f) fast = false;
    }

    float h[8];
    #pragma unroll
    for (int j = 0; j < 8; ++j) h[j] = 0.f;

    // E = exp(-softplus(dr)) = 1/(1+exp(dr)): one exp + one rcp, and E does not
    // wait on the log that produces dt.
    #define SCAN_LOAD                                                     \
      float4 q0 = *(const float4*)(smem + 18432 + l*272 + 256);           \
      float4 b0 = *(const float4*)(sBCf + l*36 + p*8);                    \
      float4 b1 = *(const float4*)(sBCf + l*36 + p*8 + 4);                \
      float4 c0 = *(const float4*)(sBCf + l*36 + 16 + p*8);               \
      float4 c1 = *(const float4*)(sBCf + l*36 + 16 + p*8 + 4);           \
      float Bv[8] = {b0.x,b0.y,b0.z,b0.w, b1.x,b1.y,b1.z,b1.w};           \
      float Cv[8] = {c0.x,c0.y,c0.z,c0.w, c1.x,c1.y,c1.z,c1.w};           \
      float dr = q0.x*dw0 + q0.y*dw1 + q0.z*dw2 + q0.w*dw3 + db;          \
      float te = __expf(dr);                                              \
      float dt = (dr > 20.f) ? dr : __logf(1.f + te);                     \
      float u = bf2f(sUC[l*136 + d]);                                     \
      float dtu = dt * u;

    if (fast) {
      for (int l = 0; l < 128; ++l) {
        SCAN_LOAD
        float E = fastrcp(1.f + te);
        float E2 = E*E, E4 = E2*E2, E8 = E4*E4;
        float e = p ? E8 : 1.f;
        float yp = 0.f;
        #pragma unroll
        for (int j = 0; j < 8; ++j) {
          e *= E;
          h[j] = h[j]*e + dtu*Bv[j];
          yp += h[j]*Cv[j];
        }
        float ysum = yp + __shfl_xor(yp, 1, 64);
        if (p == 0) sUC[l*136 + d] = f2bf(ysum + u*dpv);
      }
    } else {
      for (int l = 0; l < 128; ++l) {
        SCAN_LOAD
        float yp = 0.f;
        #pragma unroll
        for (int j = 0; j < 8; ++j) {
          float ej = __expf(dt*Av[j]);
          h[j] = h[j]*ej + dtu*Bv[j];
          yp += h[j]*Cv[j];
        }
        float ysum = yp + __shfl_xor(yp, 1, 64);
        if (p == 0) sUC[l*136 + d] = f2bf(ysum + u*dpv);
      }
    }
    #undef SCAN_LOAD
  }
  __syncthreads();

  // ---- phase 6: yf = y * silu(z) from registers; dir-dependent YF layout.
  //      dir 0/1: [n_all][l][d]; dir 2/3: transposed [dir][b*128+h][w][d].
  #pragma unroll
  for (int tt = 0; tt < 2; ++tt) {
    const int st = tt ? st1 : st0;
    size_t rowbase;
    if (dir < 2)       rowbase = ((size_t)n_all*128 + st)*128;
    else if (dir == 2) rowbase = ((size_t)(512 + b*128 + st)*128 + r)*128;
    else               rowbase = ((size_t)(768 + b*128 + (127-st))*128 + r)*128;
    #pragma unroll
    for (int k = 0; k < 8; ++k) {
      const int dz = 16*k + quad*4;
      uint2 yv = *(const uint2*)(sUC + st*136 + dz);
      float y0 = __uint_as_float(yv.x << 16);
      float y1 = __uint_as_float(yv.x & 0xffff0000u);
      float y2 = __uint_as_float(yv.y << 16);
      float y3 = __uint_as_float(yv.y & 0xffff0000u);
      unsigned int z01 = zpk[tt][k][0], z23 = zpk[tt][k][1];
      float z0 = __uint_as_float(z01 << 16);
      float z1 = __uint_as_float(z01 & 0xffff0000u);
      float z2 = __uint_as_float(z23 << 16);
      float z3 = __uint_as_float(z23 & 0xffff0000u);
      uint2 ov;
      ov.x = pk2bf(y0*z0, y1*z1);
      ov.y = pk2bf(y2*z2, y3*z3);
      *(uint2*)(YF + rowbase + dz) = ov;
    }
  }
}

// ---------------------------------------------------------------- K3 (MFMA fuse + LN)
__global__ __launch_bounds__(256, 2) void k3_fuse(
    const unsigned short* __restrict__ YF, const unsigned short* __restrict__ MT16,
    const float* __restrict__ fuse_b, const float* __restrict__ ln_g,
    const float* __restrict__ ln_b, float* __restrict__ out)
{
  __shared__ __align__(16) unsigned short sYB[64*520];   // 66,560 B

  const int tid = threadIdx.x;
  const int blk = blockIdx.x;             // 512
  const int b = blk >> 8;
  const int rr2 = blk & 255;
  const int h = rr2 >> 1;
  const int w0 = (rr2 & 1) * 64;

  for (int f = tid*8; f < 32768; f += 2048) {
    int dirg = f >> 13;
    int rem = f & 8191;
    int tok = rem >> 7;
    int dd = rem & 127;
    int X = (dirg == 1) ? (127 - w0 - tok) : (w0 + tok);
    size_t base = ((size_t)(dirg*256 + b*128 + h)*128 + X)*128 + dd;
    *(uint4*)(sYB + tok*520 + dirg*128 + dd) = *(const uint4*)(YF + base);
  }
  __syncthreads();

  const int wave = tid >> 6;
  const int lane = tid & 63;
  const int m16 = lane & 15;
  const int quad = lane >> 4;
  const int tok = wave*16 + m16;

  short8 bfr[16];
  #pragma unroll
  for (int jt = 0; jt < 16; ++jt)
    bfr[jt] = *(const short8*)(sYB + tok*520 + jt*32 + quad*8);

  float facc[4][4];
  #pragma unroll
  for (int mt = 0; mt < 4; ++mt) {
    f32x4 acc = {0.f, 0.f, 0.f, 0.f};
    #pragma unroll
    for (int jt = 0; jt < 16; ++jt) {
      short8 af = *(const short8*)(MT16 + (size_t)(mt*16 + m16)*512 + jt*32 + quad*8);
      acc = __builtin_amdgcn_mfma_f32_16x16x32_bf16(af, bfr[jt], acc, 0, 0, 0);
    }
    facc[mt][0] = acc[0]; facc[mt][1] = acc[1]; facc[mt][2] = acc[2]; facc[mt][3] = acc[3];
  }

  float fv[16];
  float s1 = 0.f, s2 = 0.f;
  #pragma unroll
  for (int mt = 0; mt < 4; ++mt)
    #pragma unroll
    for (int rr = 0; rr < 4; ++rr) {
      int o = mt*16 + quad*4 + rr;
      float v = facc[mt][rr] + fuse_b[o];
      fv[mt*4 + rr] = v;
      s1 += v; s2 += v*v;
    }
  s1 += __shfl_xor(s1, 16, 64); s1 += __shfl_xor(s1, 32, 64);
  s2 += __shfl_xor(s2, 16, 64); s2 += __shfl_xor(s2, 32, 64);
  float mu = s1 * (1.f/64.f);
  float var = s2 * (1.f/64.f) - mu*mu;
  float rs = rsqrtf(var + 1e-5f);

  #pragma unroll
  for (int mt = 0; mt < 4; ++mt)
    #pragma unroll
    for (int rr = 0; rr < 4; ++rr) {
      int o = mt*16 + quad*4 + rr;
      float v = (fv[mt*4 + rr] - mu) * rs * ln_g[o] + ln_b[o];
      out[((size_t)(b*64 + o)*128 + h)*128 + (w0 + tok)] = siluf(v);
    }
}

// ---------------------------------------------------------------- host
extern "C" void kernel_launch(void* const* d_in, const int* in_sizes, int n_in,
                              void* d_out, int out_size, void* d_ws, size_t ws_size,
                              hipStream_t stream) {
  const float* x      = (const float*)d_in[0];
  const float* in_w   = (const float*)d_in[1];
  const float* conv_w = (const float*)d_in[2];
  const float* conv_b = (const float*)d_in[3];
  const float* xp_w   = (const float*)d_in[4];
  const float* dtp_w  = (const float*)d_in[5];
  const float* dtp_b  = (const float*)d_in[6];
  const float* A_log  = (const float*)d_in[7];
  const float* Dp     = (const float*)d_in[8];
  const float* out_w  = (const float*)d_in[9];
  const float* fuse_w = (const float*)d_in[10];
  const float* fuse_b = (const float*)d_in[11];
  const float* ln_g   = (const float*)d_in[12];
  const float* ln_b   = (const float*)d_in[13];
  float* out = (float*)d_out;

  // ws layout (BYTES):
  char* ws = (char*)d_ws;
  unsigned short* YF   = (unsigned short*)(ws);              // 33,554,432 (yf, dir-layouts)
  unsigned short* MT16 = (unsigned short*)(ws + 33554432);   //     65,536
  unsigned short* W16  = (unsigned short*)(ws + 33619968);   //    131,072
  unsigned short* XW16 = (unsigned short*)(ws + 33751040);   //     49,152
  unsigned short* XH   = (unsigned short*)(ws + 33800192);   //  4,194,304 (xhwc16)
  unsigned short* XWt  = (unsigned short*)(ws + 37994496);   //  4,194,304 (xwhc16)
  // total 42,188,800 B

  k0_prep<<<dim3(420), dim3(256), 0, stream>>>(out_w, fuse_w, in_w, xp_w, x,
                                               MT16, W16, XW16, XH);
  kT2<<<dim3(256), dim3(256), 0, stream>>>(XH, XWt);
  k1_front<<<dim3(1024), dim3(256), 0, stream>>>(XH, XWt, W16, XW16, conv_w, conv_b,
                                                 dtp_w, dtp_b, A_log, Dp, YF);
  k3_fuse<<<dim3(512), dim3(256), 0, stream>>>(YF, MT16, fuse_b, ln_g, ln_b, out);
}